// Round 2
// baseline (730.122 us; speedup 1.0000x reference)
//
#include <hip/hip_runtime.h>
#include <cstdint>
#include <cstddef>

constexpr int F_IN  = 512;
constexpr int D_EMB = 128;
constexpr int D_HID = 64;
constexpr int N_CLS = 32;

typedef __attribute__((ext_vector_type(8))) short short8;
typedef __attribute__((ext_vector_type(4))) float floatx4;

__device__ inline unsigned short f2bf(float f) {
  union { float f; uint32_t u; } v; v.f = f;
  uint32_t r = v.u + 0x7FFF + ((v.u >> 16) & 1);   // round-to-nearest-even
  return (unsigned short)(r >> 16);
}

// ---- W1 -> fragment-linear bf16: Wt2[kc8][ct][ks][lane] of short8 ----------
__global__ __launch_bounds__(256) void wt_kernel(
    const float* __restrict__ W1, short8* __restrict__ Wt2)
{
  int idx = blockIdx.x * 256 + threadIdx.x;     // 0..8191
  int kc8 = idx >> 10, lin = idx & 1023;
  int ct = lin >> 7, rem = lin & 127, ks = rem >> 6, ln = rem & 63;
  int col = ct * 16 + (ln & 15);
  int k0 = kc8 * 64 + ks * 32 + (ln >> 4) * 8;
  short8 s;
#pragma unroll
  for (int j = 0; j < 8; ++j)
    s[j] = (short)f2bf(W1[(size_t)(k0 + j) * D_EMB + col]);
  Wt2[idx] = s;
}

// ---- lin1 MFMA: H1 = relu(X @ W1 + b1) -------------------------------------
// X staged through LDS (coalesced, XOR-swizzled); software-pipelined:
// next K-tile's global loads (X + W frags -> regs) are ISSUED before the
// MFMA compute of the current tile, so HBM latency hides under compute
// (T14 async-STAGE split; vmcnt lands at next iteration's convert).
__global__ __launch_bounds__(256) void lin1_mfma_kernel(
    const float* __restrict__ X, const short8* __restrict__ Wt2,
    const float* __restrict__ b1, float* __restrict__ H1, int n)
{
  __shared__ short8 Ws[1024];   // 16 KB: [ct(8)][ks(2)][lane(64)]
  __shared__ short8 Xs[1024];   // 16 KB: 128 rows x 64 bf16 cols, swizzled

  const int t = threadIdx.x;
  const int wave = t >> 6, lane = t & 63;
  const int quad = lane >> 4, mrow = lane & 15;
  const int node0 = blockIdx.x * 128;
  const int rloc = (wave >> 1) * 64;            // wave-pair local row base
  const int cw = (wave & 1) * 4;

  // staging assignment: group g = t + i*256 (i<4); row = g>>3, col8 = g&7
  const float* sp[4];
  int soff[4];
#pragma unroll
  for (int i = 0; i < 4; ++i) {
    int g = t + i * 256;
    int row = g >> 3, col8 = g & 7;
    soff[i] = row * 128 + ((col8 * 16) ^ ((row & 7) << 4));
    int gr = node0 + row; if (gr >= n) gr = n - 1;
    sp[i] = &X[(size_t)gr * F_IN + col8 * 8];
  }

  floatx4 acc[4][4];
#pragma unroll
  for (int i = 0; i < 4; ++i)
#pragma unroll
    for (int j = 0; j < 4; ++j) acc[i][j] = (floatx4){0.f, 0.f, 0.f, 0.f};

  float4 xr[4][2];      // X prefetch regs (current tile)
  short8 wr[4];         // W prefetch regs (current tile)

#pragma unroll
  for (int i = 0; i < 4; ++i) {           // prologue: tile 0
    const float* p = sp[i];
    xr[i][0] = *(const float4*)p;
    xr[i][1] = *(const float4*)(p + 4);
    wr[i] = Wt2[t + i * 256];
  }

  for (int kc8 = 0; kc8 < 8; ++kc8) {
    // convert current tile (forces vmcnt wait for this tile's loads only)
    short8 s8[4];
#pragma unroll
    for (int i = 0; i < 4; ++i) {
      s8[i][0] = (short)f2bf(xr[i][0].x); s8[i][1] = (short)f2bf(xr[i][0].y);
      s8[i][2] = (short)f2bf(xr[i][0].z); s8[i][3] = (short)f2bf(xr[i][0].w);
      s8[i][4] = (short)f2bf(xr[i][1].x); s8[i][5] = (short)f2bf(xr[i][1].y);
      s8[i][6] = (short)f2bf(xr[i][1].z); s8[i][7] = (short)f2bf(xr[i][1].w);
    }
    __syncthreads();                      // WAR: prev tile's compute done
#pragma unroll
    for (int i = 0; i < 4; ++i) {
      *(short8*)((char*)Xs + soff[i]) = s8[i];
      Ws[t + i * 256] = wr[i];
    }
    __syncthreads();                      // tile visible

    // issue NEXT tile's loads before compute (latency hides under MFMAs)
    if (kc8 < 7) {
#pragma unroll
      for (int i = 0; i < 4; ++i) {
        const float* p = sp[i] + (kc8 + 1) * 64;
        xr[i][0] = *(const float4*)p;
        xr[i][1] = *(const float4*)(p + 4);
        wr[i] = Wt2[(kc8 + 1) * 1024 + t + i * 256];
      }
    }

#pragma unroll
    for (int ks = 0; ks < 2; ++ks) {
      short8 af[4], bf[4];
#pragma unroll
      for (int rt = 0; rt < 4; ++rt) {
        int row = rloc + rt * 16 + mrow;
        int byteoff = row * 128 + ((ks * 64 + quad * 16) ^ ((row & 7) << 4));
        af[rt] = *(const short8*)((const char*)Xs + byteoff);
      }
#pragma unroll
      for (int c = 0; c < 4; ++c)
        bf[c] = Ws[((cw + c) * 2 + ks) * 64 + lane];
#pragma unroll
      for (int rt = 0; rt < 4; ++rt)
#pragma unroll
        for (int c = 0; c < 4; ++c)
          acc[rt][c] = __builtin_amdgcn_mfma_f32_16x16x32_bf16(
              af[rt], bf[c], acc[rt][c], 0, 0, 0);
    }
  }

  const int rowbase = node0 + rloc;
#pragma unroll
  for (int ct = 0; ct < 4; ++ct) {
    int col = (cw + ct) * 16 + mrow;
    float bias = b1[col];
#pragma unroll
    for (int rt = 0; rt < 4; ++rt) {
#pragma unroll
      for (int r = 0; r < 4; ++r) {
        int gn = rowbase + rt * 16 + quad * 4 + r;
        if (gn < n)
          H1[(size_t)gn * D_EMB + col] = fmaxf(acc[rt][ct][r] + bias, 0.f);
      }
    }
  }
}

// -------- mm: P[n,64](fp32) = f(In[n,K]) @ W[K,64] --------------------------
template<int K, bool PRE>
__global__ __launch_bounds__(256) void mm_kernel(
    const float* __restrict__ In, const int* __restrict__ deg,
    const float* __restrict__ bin, const float* __restrict__ W,
    float* __restrict__ Out, int n)
{
  __shared__ float Hs[64][K + 4];
  __shared__ float Ws[K][64];
  const int t = threadIdx.x;
  const int node0 = blockIdx.x * 64;
  constexpr int KQ = K / 4;

#pragma unroll
  for (int i = 0; i < (64 * KQ) / 256; ++i) {
    int lin = t + i * 256;
    int node = lin / KQ, kq = lin % KQ;
    int gn = node0 + node;
    float4 v = make_float4(0.f, 0.f, 0.f, 0.f);
    if (gn < n) {
      v = *(const float4*)&In[(size_t)gn * K + kq * 4];
      if (PRE) {
        float rd = 1.f / fmaxf((float)deg[gn], 1.f);
        v.x = fmaxf(v.x * rd + bin[kq * 4 + 0], 0.f);
        v.y = fmaxf(v.y * rd + bin[kq * 4 + 1], 0.f);
        v.z = fmaxf(v.z * rd + bin[kq * 4 + 2], 0.f);
        v.w = fmaxf(v.w * rd + bin[kq * 4 + 3], 0.f);
      }
    }
    *(float4*)&Hs[node][kq * 4] = v;
  }
#pragma unroll
  for (int i = 0; i < (K * 64) / 1024; ++i) {
    int lin = t + i * 256;
    ((float4*)&Ws[0][0])[lin] = ((const float4*)W)[lin];
  }
  __syncthreads();

  const int rg = t >> 4, cg = t & 15;
  float acc[4][4];
#pragma unroll
  for (int i = 0; i < 4; ++i)
#pragma unroll
    for (int j = 0; j < 4; ++j) acc[i][j] = 0.f;

#pragma unroll 8
  for (int k = 0; k < K; ++k) {
    float a[4] = {Hs[rg*4+0][k], Hs[rg*4+1][k], Hs[rg*4+2][k], Hs[rg*4+3][k]};
    float4 b = *(const float4*)&Ws[k][cg * 4];
#pragma unroll
    for (int i = 0; i < 4; ++i) {
      acc[i][0] += a[i]*b.x; acc[i][1] += a[i]*b.y;
      acc[i][2] += a[i]*b.z; acc[i][3] += a[i]*b.w;
    }
  }
#pragma unroll
  for (int i = 0; i < 4; ++i) {
    int gn = node0 + rg * 4 + i;
    if (gn < n) {
      float4 o = make_float4(acc[i][0], acc[i][1], acc[i][2], acc[i][3]);
      *(float4*)&Out[(size_t)gn * 64 + cg * 4] = o;
    }
  }
}

// ============== CSR build: bucketed, no global scatter ======================
// bucket = dst >> 9 (512 nodes/bucket); chunk = 8192 edges/block.
// G[b*B + blk] = count of chunk blk's edges in bucket b (bucket-major).

__global__ __launch_bounds__(256) void hist_kernel(
    const int* __restrict__ dst, int* __restrict__ G, int nE, int B, int NB)
{
  __shared__ int h[256];
  int blk = blockIdx.x, t = threadIdx.x;
  h[t] = 0;
  __syncthreads();
  int base = blk * 8192;
  int lim = min(8192, nE - base);
  for (int i = t; i < lim; i += 256)
    atomicAdd(&h[dst[base + i] >> 9], 1);
  __syncthreads();
  if (t < NB) G[t * B + blk] = h[t];
}

// generic scan (256/block): excl-in-block + block sums
__global__ __launch_bounds__(256) void scan1_kernel(
    const int* __restrict__ in, int* __restrict__ out,
    int* __restrict__ bsum, int n)
{
  __shared__ int sh[256];
  int t = threadIdx.x;
  int i = blockIdx.x * 256 + t;
  int c = (i < n) ? in[i] : 0;
  sh[t] = c;
  __syncthreads();
#pragma unroll
  for (int off = 1; off < 256; off <<= 1) {
    int v = 0;
    if (t >= off) v = sh[t - off];
    __syncthreads();
    if (t >= off) sh[t] += v;
    __syncthreads();
  }
  if (i < n) out[i] = sh[t] - c;
  if (t == 255) bsum[blockIdx.x] = sh[255];
}

__global__ __launch_bounds__(256) void scan2_kernel(int* __restrict__ bsum, int nb)
{
  __shared__ int sh[256];
  __shared__ int carry;
  int t = threadIdx.x;
  if (t == 0) carry = 0;
  __syncthreads();
  for (int base = 0; base < nb; base += 256) {
    int i = base + t;
    int v = (i < nb) ? bsum[i] : 0;
    sh[t] = v;
    __syncthreads();
#pragma unroll
    for (int off = 1; off < 256; off <<= 1) {
      int u = 0;
      if (t >= off) u = sh[t - off];
      __syncthreads();
      if (t >= off) sh[t] += u;
      __syncthreads();
    }
    int c0 = carry;
    int incl = sh[t], total = sh[255];
    if (i < nb) bsum[i] = c0 + incl - v;
    __syncthreads();
    if (t == 0) carry = c0 + total;
    __syncthreads();
  }
  if (t == 0) bsum[nb] = carry;
}

__global__ __launch_bounds__(256) void scan3_kernel(
    int* __restrict__ W, const int* __restrict__ bsum, int NG, int nb)
{
  int i = blockIdx.x * 256 + threadIdx.x;
  if (i < NG) W[i] += bsum[i >> 8];
  else if (i == NG) W[NG] = bsum[nb];
}

// scatter edges into bucket-major pair array; block-exclusive regions
__global__ __launch_bounds__(256) void scatter2_kernel(
    const int* __restrict__ src, const int* __restrict__ dst,
    const int* __restrict__ W, int2* __restrict__ EP, int nE, int B, int NB)
{
  __shared__ int cur[256];
  int blk = blockIdx.x, t = threadIdx.x;
  if (t < NB) cur[t] = W[t * B + blk];
  __syncthreads();
  int base = blk * 8192;
  int lim = min(8192, nE - base);
  for (int i = t; i < lim; i += 256) {
    int s = src[base + i], d = dst[base + i];
    int slot = atomicAdd(&cur[d >> 9], 1);
    EP[slot] = make_int2(s, d);
  }
}

// per-bucket: cnt/offs from LDS hist+scan; adj fill in block-local window
__global__ __launch_bounds__(256) void fillc_kernel(
    const int2* __restrict__ EP, const int* __restrict__ W,
    int* __restrict__ cnt, int* __restrict__ offs, int* __restrict__ adj,
    int n, int nE, int B, int NB)
{
  __shared__ int h[512];
  int b = blockIdx.x, t = threadIdx.x;
  int segStart = W[b * B];
  int segEnd = (b == NB - 1) ? nE : W[(b + 1) * B];
  int nodeBase = b << 9;

  h[t] = 0; h[t + 256] = 0;
  __syncthreads();
  for (int i = segStart + t; i < segEnd; i += 256)
    atomicAdd(&h[EP[i].y - nodeBase], 1);
  __syncthreads();
  int c0 = h[t], c1 = h[t + 256];
#pragma unroll
  for (int off = 1; off < 512; off <<= 1) {
    int a = (t >= off) ? h[t - off] : 0;
    int bb = (t + 256 >= off) ? h[t + 256 - off] : 0;
    __syncthreads();
    h[t] += a; h[t + 256] += bb;
    __syncthreads();
  }
  int e0 = h[t] - c0, e1 = h[t + 256] - c1;   // exclusive
  int g0 = nodeBase + t, g1 = nodeBase + t + 256;
  if (g0 < n) { cnt[g0] = c0; offs[g0] = segStart + e0; }
  if (g1 < n) { cnt[g1] = c1; offs[g1] = segStart + e1; }
  if (b == 0 && t == 0) offs[n] = nE;
  __syncthreads();
  h[t] = e0; h[t + 256] = e1;                 // cursors
  __syncthreads();
  for (int i = segStart + t; i < segEnd; i += 256) {
    int2 p = EP[i];
    int slot = atomicAdd(&h[p.y - nodeBase], 1);
    adj[segStart + slot] = p.x;
  }
}

// ---------------- gather: A[d] = sum_{s in adj[d]} P[s]  (wave per node) ----
__global__ __launch_bounds__(256) void gather_kernel(
    const float* __restrict__ P, const int* __restrict__ offs,
    const int* __restrict__ adj, float* __restrict__ A, int n)
{
  int node = (blockIdx.x * 256 + threadIdx.x) >> 6;
  int lane = threadIdx.x & 63;
  if (node >= n) return;
  int beg = offs[node], end = offs[node + 1];
  float acc0 = 0.f, acc1 = 0.f;
  int j = beg;
  while (j < end) {
    int m = min(end - j, 64);
    int idx = (lane < m) ? adj[j + lane] : 0;
    int q = 0;
    for (; q + 1 < m; q += 2) {
      int s0 = __shfl(idx, q, 64);
      int s1 = __shfl(idx, q + 1, 64);
      acc0 += P[(size_t)s0 * 64 + lane];
      acc1 += P[(size_t)s1 * 64 + lane];
    }
    if (q < m) {
      int s0 = __shfl(idx, q, 64);
      acc0 += P[(size_t)s0 * 64 + lane];
    }
    j += m;
  }
  A[(size_t)node * 64 + lane] = acc0 + acc1;
}

// ---- conv3 epilogue: H4 = relu(A/deg + bc3); accumulate sum/sumsq ----------
__global__ __launch_bounds__(256) void post3_kernel(
    const float* __restrict__ A, const int* __restrict__ deg,
    const float* __restrict__ bc3, float* __restrict__ H4,
    float* __restrict__ stats, int n)
{
  int t = threadIdx.x;
  int f = t & 63, q = t >> 6;
  float b = bc3[f];
  float s = 0.f, s2 = 0.f;
  for (int node = blockIdx.x * 4 + q; node < n; node += gridDim.x * 4) {
    float v = fmaxf(A[(size_t)node * 64 + f] / fmaxf((float)deg[node], 1.f) + b, 0.f);
    H4[(size_t)node * 64 + f] = v;
    s += v; s2 += v * v;
  }
  __shared__ float red[2][4][64];
  red[0][q][f] = s; red[1][q][f] = s2;
  __syncthreads();
  if (t < 128) {
    int which = t >> 6, ff = t & 63;
    float a = red[which][0][ff] + red[which][1][ff] +
              red[which][2][ff] + red[which][3][ff];
    atomicAdd(&stats[which * 64 + ff], a);
  }
}

// ---- fold batchnorm into W2 ------------------------------------------------
__global__ __launch_bounds__(256) void fold_kernel(
    const float* __restrict__ stats, const float* __restrict__ gamma,
    const float* __restrict__ beta, const float* __restrict__ W2,
    const float* __restrict__ b2, float* __restrict__ W2f,
    float* __restrict__ b2f, int n)
{
  __shared__ float rsg[64], corr[64];
  int t = threadIdx.x;
  if (t < 64) {
    float m = stats[t] / (float)n;
    float var = stats[64 + t] / (float)n - m * m;
    float rs = rsqrtf(var + 1e-5f);
    float g = gamma[t] * rs;
    rsg[t] = g;
    corr[t] = beta[t] - m * g;
  }
  __syncthreads();
#pragma unroll
  for (int i = 0; i < 8; ++i) {
    int lin = t + i * 256;
    int k = lin >> 5;
    W2f[lin] = rsg[k] * W2[lin];
  }
  if (t < 32) {
    float a = b2[t];
    for (int k = 0; k < 64; ++k) a += corr[k] * W2[k * 32 + t];
    b2f[t] = a;
  }
}

// ---- final: out = relu(H4 @ W2f + b2f) @ W3 + b3 ---------------------------
__global__ __launch_bounds__(256) void final_kernel(
    const float* __restrict__ H4, const float* __restrict__ W2f,
    const float* __restrict__ b2f, const float* __restrict__ W3,
    const float* __restrict__ b3, float* __restrict__ Out, int n)
{
  __shared__ float Hs[64][68];
  __shared__ float W2s[64][32];
  __shared__ float W3s[32][32];
  __shared__ float Us[64][36];
  __shared__ float b2s[32], b3s[32];
  const int t = threadIdx.x;
  const int node0 = blockIdx.x * 64;

#pragma unroll
  for (int i = 0; i < 4; ++i) {
    int lin = t + i * 256;
    int node = lin >> 4, kq = lin & 15;
    float4 v = make_float4(0.f, 0.f, 0.f, 0.f);
    if (node0 + node < n)
      v = *(const float4*)&H4[(size_t)(node0 + node) * 64 + kq * 4];
    *(float4*)&Hs[node][kq * 4] = v;
  }
#pragma unroll
  for (int i = 0; i < 2; ++i) {
    int lin = t + i * 256;
    ((float4*)&W2s[0][0])[lin] = ((const float4*)W2f)[lin];
  }
  ((float4*)&W3s[0][0])[t & 255] = ((const float4*)W3)[t & 255];
  if (t < 32) { b2s[t] = b2f[t]; b3s[t] = b3[t]; }
  __syncthreads();

  const int rg = t >> 4, cg = t & 15;
  float acc[4][2] = {{0.f,0.f},{0.f,0.f},{0.f,0.f},{0.f,0.f}};
#pragma unroll 8
  for (int k = 0; k < 64; ++k) {
    float a[4] = {Hs[rg*4+0][k], Hs[rg*4+1][k], Hs[rg*4+2][k], Hs[rg*4+3][k]};
    float w0 = W2s[k][cg*2], w1 = W2s[k][cg*2+1];
#pragma unroll
    for (int i = 0; i < 4; ++i) { acc[i][0] += a[i]*w0; acc[i][1] += a[i]*w1; }
  }
#pragma unroll
  for (int i = 0; i < 4; ++i) {
    Us[rg*4+i][cg*2+0] = fmaxf(acc[i][0] + b2s[cg*2+0], 0.f);
    Us[rg*4+i][cg*2+1] = fmaxf(acc[i][1] + b2s[cg*2+1], 0.f);
  }
  __syncthreads();

  float acc2[4][2] = {{0.f,0.f},{0.f,0.f},{0.f,0.f},{0.f,0.f}};
#pragma unroll
  for (int k = 0; k < 32; ++k) {
    float a[4] = {Us[rg*4+0][k], Us[rg*4+1][k], Us[rg*4+2][k], Us[rg*4+3][k]};
    float w0 = W3s[k][cg*2], w1 = W3s[k][cg*2+1];
#pragma unroll
    for (int i = 0; i < 4; ++i) { acc2[i][0] += a[i]*w0; acc2[i][1] += a[i]*w1; }
  }
  float (*Os)[36] = (float(*)[36])Hs;
#pragma unroll
  for (int i = 0; i < 4; ++i) {
    Os[rg*4+i][cg*2+0] = acc2[i][0] + b3s[cg*2+0];
    Os[rg*4+i][cg*2+1] = acc2[i][1] + b3s[cg*2+1];
  }
  __syncthreads();
#pragma unroll
  for (int i = 0; i < 2; ++i) {
    int lin = t + i * 256;
    int node = lin >> 3, c4 = lin & 7;
    if (node0 + node < n)
      *(float4*)&Out[(size_t)(node0 + node) * 32 + c4 * 4] =
          *(float4*)&Os[node][c4 * 4];
  }
}

// ---------------------------------------------------------------------------
extern "C" void kernel_launch(void* const* d_in, const int* in_sizes, int n_in,
                              void* d_out, int out_size, void* d_ws, size_t ws_size,
                              hipStream_t stream)
{
  const float* X     = (const float*)d_in[0];
  const float* W1    = (const float*)d_in[1];
  const float* b1    = (const float*)d_in[2];
  const float* Wc1   = (const float*)d_in[3];
  const float* bc1   = (const float*)d_in[4];
  const float* Wc2   = (const float*)d_in[5];
  const float* bc2   = (const float*)d_in[6];
  const float* Wc3   = (const float*)d_in[7];
  const float* bc3   = (const float*)d_in[8];
  const float* gamma = (const float*)d_in[9];
  const float* beta  = (const float*)d_in[10];
  const float* W2    = (const float*)d_in[11];
  const float* b2    = (const float*)d_in[12];
  const float* W3    = (const float*)d_in[13];
  const float* b3    = (const float*)d_in[14];
  const int*   ei    = (const int*)d_in[15];

  const int n  = in_sizes[0] / F_IN;
  const int nE = in_sizes[15] / 2;
  const int* src  = ei;
  const int* dstv = ei + nE;

  const int NB = (n + 511) >> 9;          // buckets of 512 nodes
  const int B  = (nE + 8191) >> 13;       // chunks of 8192 edges
  const int NG = NB * B;
  const int nbG = (NG + 255) / 256;

  float* ws    = (float*)d_ws;
  float* H1    = ws;                                   // n*128 (H4 reuses)
  float* P     = H1 + (size_t)n * D_EMB;               // n*64 fp32
  float* A     = P  + (size_t)n * D_HID;               // n*64
  float* stats = A  + (size_t)n * D_HID;               // 128
  float* W2f   = stats + 128;                          // 2048
  float* b2f   = W2f + 2048;                           // 32
  int*   cnt   = (int*)(b2f + 32);                     // n
  int*   offs  = cnt + n;                              // n+1
  int*   G     = offs + n + 1;                         // NG
  int*   W     = G + NG;                               // NG+1
  int*   bsum  = W + NG + 1;                           // nbG+1
  int*   adj   = bsum + nbG + 1;                       // nE
  uintptr_t epAddr = ((uintptr_t)(adj + nE) + 7) & ~(uintptr_t)7;
  int2*  EP    = (int2*)epAddr;                        // nE pairs
  short8* Wt2  = (short8*)(EP + nE);                   // 128KB
  float* H4    = H1;                                   // reuse H1

  const int nb  = (n + 63) / 64;
  const int gatherBlocks = (int)(((long long)n * 64 + 255) / 256);

  hipMemsetAsync(stats, 0, 128 * sizeof(float), stream);

  // W1 -> fragment-linear bf16, then bf16-MFMA lin1
  wt_kernel<<<32, 256, 0, stream>>>(W1, Wt2);
  lin1_mfma_kernel<<<(n + 127) / 128, 256, 0, stream>>>(X, Wt2, b1, H1, n);

  // CSR build (bucketed, no global scatter)
  hist_kernel<<<B, 256, 0, stream>>>(dstv, G, nE, B, NB);
  scan1_kernel<<<nbG, 256, 0, stream>>>(G, W, bsum, NG);
  scan2_kernel<<<1, 256, 0, stream>>>(bsum, nbG);
  scan3_kernel<<<(NG + 256) / 256, 256, 0, stream>>>(W, bsum, NG, nbG);
  scatter2_kernel<<<B, 256, 0, stream>>>(src, dstv, W, EP, nE, B, NB);
  fillc_kernel<<<NB, 256, 0, stream>>>(EP, W, cnt, offs, adj, n, nE, B, NB);

  // conv1: P = H1 @ Wc1 ; A = gather-sum(P)
  mm_kernel<128, false><<<nb, 256, 0, stream>>>(H1, nullptr, nullptr, Wc1, P, n);
  gather_kernel<<<gatherBlocks, 256, 0, stream>>>(P, offs, adj, A, n);

  // conv2
  mm_kernel<64, true><<<nb, 256, 0, stream>>>(A, cnt, bc1, Wc2, P, n);
  gather_kernel<<<gatherBlocks, 256, 0, stream>>>(P, offs, adj, A, n);

  // conv3
  mm_kernel<64, true><<<nb, 256, 0, stream>>>(A, cnt, bc2, Wc3, P, n);
  gather_kernel<<<gatherBlocks, 256, 0, stream>>>(P, offs, adj, A, n);

  // conv3 epilogue + batch stats
  post3_kernel<<<256, 256, 0, stream>>>(A, cnt, bc3, H4, stats, n);

  // fold batchnorm into W2, then fused lin2+lin3
  fold_kernel<<<1, 256, 0, stream>>>(stats, gamma, beta, W2, b2, W2f, b2f, n);
  final_kernel<<<nb, 256, 0, stream>>>(H4, W2f, b2f, W3, b3, (float*)d_out, n);
}

// Round 3
// 692.420 us; speedup vs baseline: 1.0545x; 1.0545x over previous
//
#include <hip/hip_runtime.h>
#include <cstdint>
#include <cstddef>

constexpr int F_IN  = 512;
constexpr int D_EMB = 128;
constexpr int D_HID = 64;
constexpr int N_CLS = 32;

typedef __attribute__((ext_vector_type(8))) short short8;
typedef __attribute__((ext_vector_type(4))) float floatx4;

__device__ inline unsigned short f2bf(float f) {
  union { float f; uint32_t u; } v; v.f = f;
  uint32_t r = v.u + 0x7FFF + ((v.u >> 16) & 1);   // round-to-nearest-even
  return (unsigned short)(r >> 16);
}

// ---- W1 -> fragment-linear bf16: Wt2[kc8][ct][ks][lane] of short8 ----------
__global__ __launch_bounds__(256) void wt_kernel(
    const float* __restrict__ W1, short8* __restrict__ Wt2)
{
  int idx = blockIdx.x * 256 + threadIdx.x;     // 0..8191
  int kc8 = idx >> 10, lin = idx & 1023;
  int ct = lin >> 7, rem = lin & 127, ks = rem >> 6, ln = rem & 63;
  int col = ct * 16 + (ln & 15);
  int k0 = kc8 * 64 + ks * 32 + (ln >> 4) * 8;
  short8 s;
#pragma unroll
  for (int j = 0; j < 8; ++j)
    s[j] = (short)f2bf(W1[(size_t)(k0 + j) * D_EMB + col]);
  Wt2[idx] = s;
}

// ---- lin1 MFMA: H1 = relu(X @ W1 + b1) -------------------------------------
__global__ __launch_bounds__(256) void lin1_mfma_kernel(
    const float* __restrict__ X, const short8* __restrict__ Wt2,
    const float* __restrict__ b1, float* __restrict__ H1, int n)
{
  __shared__ short8 Ws[1024];   // 16 KB: [ct(8)][ks(2)][lane(64)]
  __shared__ short8 Xs[1024];   // 16 KB: 128 rows x 64 bf16 cols, swizzled

  const int t = threadIdx.x;
  const int wave = t >> 6, lane = t & 63;
  const int quad = lane >> 4, mrow = lane & 15;
  const int node0 = blockIdx.x * 128;
  const int rloc = (wave >> 1) * 64;            // wave-pair local row base
  const int cw = (wave & 1) * 4;

  const float* sp[4];
  int soff[4];
#pragma unroll
  for (int i = 0; i < 4; ++i) {
    int g = t + i * 256;
    int row = g >> 3, col8 = g & 7;
    soff[i] = row * 128 + ((col8 * 16) ^ ((row & 7) << 4));
    int gr = node0 + row; if (gr >= n) gr = n - 1;
    sp[i] = &X[(size_t)gr * F_IN + col8 * 8];
  }

  floatx4 acc[4][4];
#pragma unroll
  for (int i = 0; i < 4; ++i)
#pragma unroll
    for (int j = 0; j < 4; ++j) acc[i][j] = (floatx4){0.f, 0.f, 0.f, 0.f};

  float4 xr[4][2];      // X prefetch regs (current tile)
  short8 wr[4];         // W prefetch regs (current tile)

#pragma unroll
  for (int i = 0; i < 4; ++i) {           // prologue: tile 0
    const float* p = sp[i];
    xr[i][0] = *(const float4*)p;
    xr[i][1] = *(const float4*)(p + 4);
    wr[i] = Wt2[t + i * 256];
  }

  for (int kc8 = 0; kc8 < 8; ++kc8) {
    short8 s8[4];
#pragma unroll
    for (int i = 0; i < 4; ++i) {
      s8[i][0] = (short)f2bf(xr[i][0].x); s8[i][1] = (short)f2bf(xr[i][0].y);
      s8[i][2] = (short)f2bf(xr[i][0].z); s8[i][3] = (short)f2bf(xr[i][0].w);
      s8[i][4] = (short)f2bf(xr[i][1].x); s8[i][5] = (short)f2bf(xr[i][1].y);
      s8[i][6] = (short)f2bf(xr[i][1].z); s8[i][7] = (short)f2bf(xr[i][1].w);
    }
    __syncthreads();
#pragma unroll
    for (int i = 0; i < 4; ++i) {
      *(short8*)((char*)Xs + soff[i]) = s8[i];
      Ws[t + i * 256] = wr[i];
    }
    __syncthreads();

    if (kc8 < 7) {
#pragma unroll
      for (int i = 0; i < 4; ++i) {
        const float* p = sp[i] + (kc8 + 1) * 64;
        xr[i][0] = *(const float4*)p;
        xr[i][1] = *(const float4*)(p + 4);
        wr[i] = Wt2[(kc8 + 1) * 1024 + t + i * 256];
      }
    }

#pragma unroll
    for (int ks = 0; ks < 2; ++ks) {
      short8 af[4], bf[4];
#pragma unroll
      for (int rt = 0; rt < 4; ++rt) {
        int row = rloc + rt * 16 + mrow;
        int byteoff = row * 128 + ((ks * 64 + quad * 16) ^ ((row & 7) << 4));
        af[rt] = *(const short8*)((const char*)Xs + byteoff);
      }
#pragma unroll
      for (int c = 0; c < 4; ++c)
        bf[c] = Ws[((cw + c) * 2 + ks) * 64 + lane];
#pragma unroll
      for (int rt = 0; rt < 4; ++rt)
#pragma unroll
        for (int c = 0; c < 4; ++c)
          acc[rt][c] = __builtin_amdgcn_mfma_f32_16x16x32_bf16(
              af[rt], bf[c], acc[rt][c], 0, 0, 0);
    }
  }

  const int rowbase = node0 + rloc;
#pragma unroll
  for (int ct = 0; ct < 4; ++ct) {
    int col = (cw + ct) * 16 + mrow;
    float bias = b1[col];
#pragma unroll
    for (int rt = 0; rt < 4; ++rt) {
#pragma unroll
      for (int r = 0; r < 4; ++r) {
        int gn = rowbase + rt * 16 + quad * 4 + r;
        if (gn < n)
          H1[(size_t)gn * D_EMB + col] = fmaxf(acc[rt][ct][r] + bias, 0.f);
      }
    }
  }
}

// -------- mm: P[n,64](fp32) = In[n,K] @ W[K,64]  (conv1 only, K=128) --------
template<int K>
__global__ __launch_bounds__(256) void mm_kernel(
    const float* __restrict__ In, const float* __restrict__ W,
    float* __restrict__ Out, int n)
{
  __shared__ float Hs[64][K + 4];
  __shared__ float Ws[K][64];
  const int t = threadIdx.x;
  const int node0 = blockIdx.x * 64;
  constexpr int KQ = K / 4;

#pragma unroll
  for (int i = 0; i < (64 * KQ) / 256; ++i) {
    int lin = t + i * 256;
    int node = lin / KQ, kq = lin % KQ;
    int gn = node0 + node;
    float4 v = make_float4(0.f, 0.f, 0.f, 0.f);
    if (gn < n)
      v = *(const float4*)&In[(size_t)gn * K + kq * 4];
    *(float4*)&Hs[node][kq * 4] = v;
  }
#pragma unroll
  for (int i = 0; i < (K * 64) / 1024; ++i) {
    int lin = t + i * 256;
    ((float4*)&Ws[0][0])[lin] = ((const float4*)W)[lin];
  }
  __syncthreads();

  const int rg = t >> 4, cg = t & 15;
  float acc[4][4];
#pragma unroll
  for (int i = 0; i < 4; ++i)
#pragma unroll
    for (int j = 0; j < 4; ++j) acc[i][j] = 0.f;

#pragma unroll 8
  for (int k = 0; k < K; ++k) {
    float a[4] = {Hs[rg*4+0][k], Hs[rg*4+1][k], Hs[rg*4+2][k], Hs[rg*4+3][k]};
    float4 b = *(const float4*)&Ws[k][cg * 4];
#pragma unroll
    for (int i = 0; i < 4; ++i) {
      acc[i][0] += a[i]*b.x; acc[i][1] += a[i]*b.y;
      acc[i][2] += a[i]*b.z; acc[i][3] += a[i]*b.w;
    }
  }
#pragma unroll
  for (int i = 0; i < 4; ++i) {
    int gn = node0 + rg * 4 + i;
    if (gn < n) {
      float4 o = make_float4(acc[i][0], acc[i][1], acc[i][2], acc[i][3]);
      *(float4*)&Out[(size_t)gn * 64 + cg * 4] = o;
    }
  }
}

// ======= fused gather + pre(relu,deg,bias) + matmul: Out = pre(agg(P)) @ W ==
// block = 64 dst nodes, 512 threads = 8 waves x 8 nodes/wave.
// Gather sums neighbor P rows (4-deep pipelined) into LDS with the PRE
// transform applied, then a K=64 matmul from LDS. Eliminates the A buffer.
__global__ __launch_bounds__(512) void gmm_kernel(
    const float* __restrict__ P, const int* __restrict__ offs,
    const int* __restrict__ adj, const int* __restrict__ deg,
    const float* __restrict__ bin, const float* __restrict__ W,
    float* __restrict__ Out, int n)
{
  __shared__ float Hs[64][68];
  __shared__ float Ws[64][64];
  const int t = threadIdx.x;
  const int wave = t >> 6, lane = t & 63;
  const int node0 = blockIdx.x * 64;

#pragma unroll
  for (int i = 0; i < 2; ++i) {
    int lin = t + i * 512;
    ((float4*)&Ws[0][0])[lin] = ((const float4*)W)[lin];
  }
  const float bb = bin[lane];

#pragma unroll 1
  for (int nd = 0; nd < 8; ++nd) {
    int ln = wave * 8 + nd;
    int node = node0 + ln;
    float v = 0.f;
    if (node < n) {
      int beg = offs[node], end = offs[node + 1];
      float a0 = 0.f, a1 = 0.f, a2 = 0.f, a3 = 0.f;
      int j = beg;
      while (j < end) {
        int m = min(end - j, 64);
        int idx = (lane < m) ? adj[j + lane] : 0;
        int q = 0;
        for (; q + 3 < m; q += 4) {
          int s0 = __shfl(idx, q, 64),     s1 = __shfl(idx, q + 1, 64);
          int s2 = __shfl(idx, q + 2, 64), s3 = __shfl(idx, q + 3, 64);
          a0 += P[(size_t)s0 * 64 + lane];
          a1 += P[(size_t)s1 * 64 + lane];
          a2 += P[(size_t)s2 * 64 + lane];
          a3 += P[(size_t)s3 * 64 + lane];
        }
        for (; q < m; ++q) {
          int s0 = __shfl(idx, q, 64);
          a0 += P[(size_t)s0 * 64 + lane];
        }
        j += m;
      }
      float rd = 1.f / fmaxf((float)deg[node], 1.f);
      v = fmaxf(((a0 + a2) + (a1 + a3)) * rd + bb, 0.f);
    }
    Hs[ln][lane] = v;
  }
  __syncthreads();

  const int rg = t >> 4, cg = t & 15;          // rg 0..31 -> 2 rows each
  float acc[2][4];
#pragma unroll
  for (int i = 0; i < 2; ++i)
#pragma unroll
    for (int j = 0; j < 4; ++j) acc[i][j] = 0.f;

#pragma unroll 8
  for (int k = 0; k < 64; ++k) {
    float a[2] = {Hs[rg * 2 + 0][k], Hs[rg * 2 + 1][k]};
    float4 b = *(const float4*)&Ws[k][cg * 4];
#pragma unroll
    for (int i = 0; i < 2; ++i) {
      acc[i][0] += a[i]*b.x; acc[i][1] += a[i]*b.y;
      acc[i][2] += a[i]*b.z; acc[i][3] += a[i]*b.w;
    }
  }
#pragma unroll
  for (int i = 0; i < 2; ++i) {
    int gn = node0 + rg * 2 + i;
    if (gn < n) {
      float4 o = make_float4(acc[i][0], acc[i][1], acc[i][2], acc[i][3]);
      *(float4*)&Out[(size_t)gn * 64 + cg * 4] = o;
    }
  }
}

// ======= fused gather3 + post3: H4 = relu(agg(P)/deg + bc3); stats ==========
__global__ __launch_bounds__(512) void gp_kernel(
    const float* __restrict__ P, const int* __restrict__ offs,
    const int* __restrict__ adj, const int* __restrict__ deg,
    const float* __restrict__ bc3, float* __restrict__ H4,
    float* __restrict__ stats, int n)
{
  const int t = threadIdx.x;
  const int wave = t >> 6, lane = t & 63;
  const int node0 = blockIdx.x * 64;
  const float bb = bc3[lane];
  float s = 0.f, s2 = 0.f;

#pragma unroll 1
  for (int nd = 0; nd < 8; ++nd) {
    int node = node0 + wave * 8 + nd;
    if (node >= n) break;
    int beg = offs[node], end = offs[node + 1];
    float a0 = 0.f, a1 = 0.f, a2 = 0.f, a3 = 0.f;
    int j = beg;
    while (j < end) {
      int m = min(end - j, 64);
      int idx = (lane < m) ? adj[j + lane] : 0;
      int q = 0;
      for (; q + 3 < m; q += 4) {
        int s0 = __shfl(idx, q, 64),     s1 = __shfl(idx, q + 1, 64);
        int s2i = __shfl(idx, q + 2, 64), s3 = __shfl(idx, q + 3, 64);
        a0 += P[(size_t)s0 * 64 + lane];
        a1 += P[(size_t)s1 * 64 + lane];
        a2 += P[(size_t)s2i * 64 + lane];
        a3 += P[(size_t)s3 * 64 + lane];
      }
      for (; q < m; ++q) {
        int s0 = __shfl(idx, q, 64);
        a0 += P[(size_t)s0 * 64 + lane];
      }
      j += m;
    }
    float rd = 1.f / fmaxf((float)deg[node], 1.f);
    float v = fmaxf(((a0 + a2) + (a1 + a3)) * rd + bb, 0.f);
    H4[(size_t)node * 64 + lane] = v;
    s += v; s2 += v * v;
  }

  __shared__ float red[2][8][64];
  red[0][wave][lane] = s; red[1][wave][lane] = s2;
  __syncthreads();
  if (t < 128) {
    int which = t >> 6, ff = t & 63;
    float a = 0.f;
#pragma unroll
    for (int w = 0; w < 8; ++w) a += red[which][w][ff];
    atomicAdd(&stats[which * 64 + ff], a);
  }
}

// ============== CSR build: bucketed, no global scatter ======================
// bucket = dst >> 9 (512 nodes/bucket); chunk = 8192 edges/block.
// G[b*B + blk] = count of chunk blk's edges in bucket b (bucket-major).

__global__ __launch_bounds__(256) void hist_kernel(
    const int* __restrict__ dst, int* __restrict__ G,
    float* __restrict__ stats, int nE, int B, int NB)
{
  __shared__ int h[256];
  int blk = blockIdx.x, t = threadIdx.x;
  if (blk == 0 && t < 128) stats[t] = 0.f;     // folded stats memset
  h[t] = 0;
  __syncthreads();
  int base = blk * 8192;
  int lim = min(8192, nE - base);
  for (int i = t; i < lim; i += 256)
    atomicAdd(&h[dst[base + i] >> 9], 1);
  __syncthreads();
  if (t < NB) G[t * B + blk] = h[t];
}

// generic scan (256/block): excl-in-block + block sums
__global__ __launch_bounds__(256) void scan1_kernel(
    const int* __restrict__ in, int* __restrict__ out,
    int* __restrict__ bsum, int n)
{
  __shared__ int sh[256];
  int t = threadIdx.x;
  int i = blockIdx.x * 256 + t;
  int c = (i < n) ? in[i] : 0;
  sh[t] = c;
  __syncthreads();
#pragma unroll
  for (int off = 1; off < 256; off <<= 1) {
    int v = 0;
    if (t >= off) v = sh[t - off];
    __syncthreads();
    if (t >= off) sh[t] += v;
    __syncthreads();
  }
  if (i < n) out[i] = sh[t] - c;
  if (t == 255) bsum[blockIdx.x] = sh[255];
}

__global__ __launch_bounds__(256) void scan2_kernel(int* __restrict__ bsum, int nb)
{
  __shared__ int sh[256];
  __shared__ int carry;
  int t = threadIdx.x;
  if (t == 0) carry = 0;
  __syncthreads();
  for (int base = 0; base < nb; base += 256) {
    int i = base + t;
    int v = (i < nb) ? bsum[i] : 0;
    sh[t] = v;
    __syncthreads();
#pragma unroll
    for (int off = 1; off < 256; off <<= 1) {
      int u = 0;
      if (t >= off) u = sh[t - off];
      __syncthreads();
      if (t >= off) sh[t] += u;
      __syncthreads();
    }
    int c0 = carry;
    int incl = sh[t], total = sh[255];
    if (i < nb) bsum[i] = c0 + incl - v;
    __syncthreads();
    if (t == 0) carry = c0 + total;
    __syncthreads();
  }
  if (t == 0) bsum[nb] = carry;
}

// scatter edges into bucket-major pair array; block-exclusive regions
// (bsum correction applied at read site: scan3 eliminated)
__global__ __launch_bounds__(256) void scatter2_kernel(
    const int* __restrict__ src, const int* __restrict__ dst,
    const int* __restrict__ W, const int* __restrict__ bsum,
    int2* __restrict__ EP, int nE, int B, int NB)
{
  __shared__ int cur[256];
  int blk = blockIdx.x, t = threadIdx.x;
  if (t < NB) {
    int gi = t * B + blk;
    cur[t] = W[gi] + bsum[gi >> 8];
  }
  __syncthreads();
  int base = blk * 8192;
  int lim = min(8192, nE - base);
  for (int i = t; i < lim; i += 256) {
    int s = src[base + i], d = dst[base + i];
    int slot = atomicAdd(&cur[d >> 9], 1);
    EP[slot] = make_int2(s, d);
  }
}

// per-bucket: cnt/offs from LDS hist+scan; adj fill in block-local window
__global__ __launch_bounds__(256) void fillc_kernel(
    const int2* __restrict__ EP, const int* __restrict__ W,
    const int* __restrict__ bsum,
    int* __restrict__ cnt, int* __restrict__ offs, int* __restrict__ adj,
    int n, int nE, int B, int NB)
{
  __shared__ int h[512];
  int b = blockIdx.x, t = threadIdx.x;
  int g0i = b * B;
  int segStart = W[g0i] + bsum[g0i >> 8];
  int segEnd = (b == NB - 1) ? nE : (W[g0i + B] + bsum[(g0i + B) >> 8]);
  int nodeBase = b << 9;

  h[t] = 0; h[t + 256] = 0;
  __syncthreads();
  for (int i = segStart + t; i < segEnd; i += 256)
    atomicAdd(&h[EP[i].y - nodeBase], 1);
  __syncthreads();
  int c0 = h[t], c1 = h[t + 256];
#pragma unroll
  for (int off = 1; off < 512; off <<= 1) {
    int a = (t >= off) ? h[t - off] : 0;
    int bb = (t + 256 >= off) ? h[t + 256 - off] : 0;
    __syncthreads();
    h[t] += a; h[t + 256] += bb;
    __syncthreads();
  }
  int e0 = h[t] - c0, e1 = h[t + 256] - c1;   // exclusive
  int g0 = nodeBase + t, g1 = nodeBase + t + 256;
  if (g0 < n) { cnt[g0] = c0; offs[g0] = segStart + e0; }
  if (g1 < n) { cnt[g1] = c1; offs[g1] = segStart + e1; }
  if (b == 0 && t == 0) offs[n] = nE;
  __syncthreads();
  h[t] = e0; h[t + 256] = e1;                 // cursors
  __syncthreads();
  for (int i = segStart + t; i < segEnd; i += 256) {
    int2 p = EP[i];
    int slot = atomicAdd(&h[p.y - nodeBase], 1);
    adj[segStart + slot] = p.x;
  }
}

// ---- fold batchnorm into W2 ------------------------------------------------
__global__ __launch_bounds__(256) void fold_kernel(
    const float* __restrict__ stats, const float* __restrict__ gamma,
    const float* __restrict__ beta, const float* __restrict__ W2,
    const float* __restrict__ b2, float* __restrict__ W2f,
    float* __restrict__ b2f, int n)
{
  __shared__ float rsg[64], corr[64];
  int t = threadIdx.x;
  if (t < 64) {
    float m = stats[t] / (float)n;
    float var = stats[64 + t] / (float)n - m * m;
    float rs = rsqrtf(var + 1e-5f);
    float g = gamma[t] * rs;
    rsg[t] = g;
    corr[t] = beta[t] - m * g;
  }
  __syncthreads();
#pragma unroll
  for (int i = 0; i < 8; ++i) {
    int lin = t + i * 256;
    int k = lin >> 5;
    W2f[lin] = rsg[k] * W2[lin];
  }
  if (t < 32) {
    float a = b2[t];
    for (int k = 0; k < 64; ++k) a += corr[k] * W2[k * 32 + t];
    b2f[t] = a;
  }
}

// ---- final: out = relu(H4 @ W2f + b2f) @ W3 + b3 ---------------------------
__global__ __launch_bounds__(256) void final_kernel(
    const float* __restrict__ H4, const float* __restrict__ W2f,
    const float* __restrict__ b2f, const float* __restrict__ W3,
    const float* __restrict__ b3, float* __restrict__ Out, int n)
{
  __shared__ float Hs[64][68];
  __shared__ float W2s[64][32];
  __shared__ float W3s[32][32];
  __shared__ float Us[64][36];
  __shared__ float b2s[32], b3s[32];
  const int t = threadIdx.x;
  const int node0 = blockIdx.x * 64;

#pragma unroll
  for (int i = 0; i < 4; ++i) {
    int lin = t + i * 256;
    int node = lin >> 4, kq = lin & 15;
    float4 v = make_float4(0.f, 0.f, 0.f, 0.f);
    if (node0 + node < n)
      v = *(const float4*)&H4[(size_t)(node0 + node) * 64 + kq * 4];
    *(float4*)&Hs[node][kq * 4] = v;
  }
#pragma unroll
  for (int i = 0; i < 2; ++i) {
    int lin = t + i * 256;
    ((float4*)&W2s[0][0])[lin] = ((const float4*)W2f)[lin];
  }
  ((float4*)&W3s[0][0])[t & 255] = ((const float4*)W3)[t & 255];
  if (t < 32) { b2s[t] = b2f[t]; b3s[t] = b3[t]; }
  __syncthreads();

  const int rg = t >> 4, cg = t & 15;
  float acc[4][2] = {{0.f,0.f},{0.f,0.f},{0.f,0.f},{0.f,0.f}};
#pragma unroll 8
  for (int k = 0; k < 64; ++k) {
    float a[4] = {Hs[rg*4+0][k], Hs[rg*4+1][k], Hs[rg*4+2][k], Hs[rg*4+3][k]};
    float w0 = W2s[k][cg*2], w1 = W2s[k][cg*2+1];
#pragma unroll
    for (int i = 0; i < 4; ++i) { acc[i][0] += a[i]*w0; acc[i][1] += a[i]*w1; }
  }
#pragma unroll
  for (int i = 0; i < 4; ++i) {
    Us[rg*4+i][cg*2+0] = fmaxf(acc[i][0] + b2s[cg*2+0], 0.f);
    Us[rg*4+i][cg*2+1] = fmaxf(acc[i][1] + b2s[cg*2+1], 0.f);
  }
  __syncthreads();

  float acc2[4][2] = {{0.f,0.f},{0.f,0.f},{0.f,0.f},{0.f,0.f}};
#pragma unroll
  for (int k = 0; k < 32; ++k) {
    float a[4] = {Us[rg*4+0][k], Us[rg*4+1][k], Us[rg*4+2][k], Us[rg*4+3][k]};
    float w0 = W3s[k][cg*2], w1 = W3s[k][cg*2+1];
#pragma unroll
    for (int i = 0; i < 4; ++i) { acc2[i][0] += a[i]*w0; acc2[i][1] += a[i]*w1; }
  }
  float (*Os)[36] = (float(*)[36])Hs;
#pragma unroll
  for (int i = 0; i < 4; ++i) {
    Os[rg*4+i][cg*2+0] = acc2[i][0] + b3s[cg*2+0];
    Os[rg*4+i][cg*2+1] = acc2[i][1] + b3s[cg*2+1];
  }
  __syncthreads();
#pragma unroll
  for (int i = 0; i < 2; ++i) {
    int lin = t + i * 256;
    int node = lin >> 3, c4 = lin & 7;
    if (node0 + node < n)
      *(float4*)&Out[(size_t)(node0 + node) * 32 + c4 * 4] =
          *(float4*)&Os[node][c4 * 4];
  }
}

// ---------------------------------------------------------------------------
extern "C" void kernel_launch(void* const* d_in, const int* in_sizes, int n_in,
                              void* d_out, int out_size, void* d_ws, size_t ws_size,
                              hipStream_t stream)
{
  const float* X     = (const float*)d_in[0];
  const float* W1    = (const float*)d_in[1];
  const float* b1    = (const float*)d_in[2];
  const float* Wc1   = (const float*)d_in[3];
  const float* bc1   = (const float*)d_in[4];
  const float* Wc2   = (const float*)d_in[5];
  const float* bc2   = (const float*)d_in[6];
  const float* Wc3   = (const float*)d_in[7];
  const float* bc3   = (const float*)d_in[8];
  const float* gamma = (const float*)d_in[9];
  const float* beta  = (const float*)d_in[10];
  const float* W2    = (const float*)d_in[11];
  const float* b2    = (const float*)d_in[12];
  const float* W3    = (const float*)d_in[13];
  const float* b3    = (const float*)d_in[14];
  const int*   ei    = (const int*)d_in[15];

  const int n  = in_sizes[0] / F_IN;
  const int nE = in_sizes[15] / 2;
  const int* src  = ei;
  const int* dstv = ei + nE;

  const int NB = (n + 511) >> 9;          // buckets of 512 nodes
  const int B  = (nE + 8191) >> 13;       // chunks of 8192 edges
  const int NG = NB * B;
  const int nbG = (NG + 255) / 256;

  float* ws    = (float*)d_ws;
  float* H1    = ws;                                   // n*128 (H4 reuses)
  float* Pa    = H1 + (size_t)n * D_EMB;               // n*64 fp32 (ping)
  float* Pb    = Pa + (size_t)n * D_HID;               // n*64 fp32 (pong)
  float* stats = Pb + (size_t)n * D_HID;               // 128
  float* W2f   = stats + 128;                          // 2048
  float* b2f   = W2f + 2048;                           // 32
  int*   cnt   = (int*)(b2f + 32);                     // n
  int*   offs  = cnt + n;                              // n+1
  int*   G     = offs + n + 1;                         // NG
  int*   W     = G + NG;                               // NG+1
  int*   bsum  = W + NG + 1;                           // nbG+1
  int*   adj   = bsum + nbG + 1;                       // nE
  uintptr_t epAddr = ((uintptr_t)(adj + nE) + 7) & ~(uintptr_t)7;
  int2*  EP    = (int2*)epAddr;                        // nE pairs
  short8* Wt2  = (short8*)(EP + nE);                   // 128KB
  float* H4    = H1;                                   // reuse H1

  const int nb  = (n + 63) / 64;

  // W1 -> fragment-linear bf16, then bf16-MFMA lin1
  wt_kernel<<<32, 256, 0, stream>>>(W1, Wt2);
  lin1_mfma_kernel<<<(n + 127) / 128, 256, 0, stream>>>(X, Wt2, b1, H1, n);

  // CSR build (bucketed, no global scatter; scan3 folded into read sites)
  hist_kernel<<<B, 256, 0, stream>>>(dstv, G, stats, nE, B, NB);
  scan1_kernel<<<nbG, 256, 0, stream>>>(G, W, bsum, NG);
  scan2_kernel<<<1, 256, 0, stream>>>(bsum, nbG);
  scatter2_kernel<<<B, 256, 0, stream>>>(src, dstv, W, bsum, EP, nE, B, NB);
  fillc_kernel<<<NB, 256, 0, stream>>>(EP, W, bsum, cnt, offs, adj, n, nE, B, NB);

  // conv1: Pa = H1 @ Wc1
  mm_kernel<128><<<nb, 256, 0, stream>>>(H1, Wc1, Pa, n);

  // conv2: Pb = relu(agg(Pa)/deg + bc1) @ Wc2   (fused gather+pre+mm)
  gmm_kernel<<<nb, 512, 0, stream>>>(Pa, offs, adj, cnt, bc1, Wc2, Pb, n);

  // conv3: Pa = relu(agg(Pb)/deg + bc2) @ Wc3
  gmm_kernel<<<nb, 512, 0, stream>>>(Pb, offs, adj, cnt, bc2, Wc3, Pa, n);

  // conv3 epilogue: H4 = relu(agg(Pa)/deg + bc3); batch stats
  gp_kernel<<<nb, 512, 0, stream>>>(Pa, offs, adj, cnt, bc3, H4, stats, n);

  // fold batchnorm into W2, then fused lin2+lin3
  fold_kernel<<<1, 256, 0, stream>>>(stats, gamma, beta, W2, b2, W2f, b2f, n);
  final_kernel<<<nb, 256, 0, stream>>>(H4, W2f, b2f, W3, b3, (float*)d_out, n);
}

// Round 4
// 657.776 us; speedup vs baseline: 1.1100x; 1.0527x over previous
//
#include <hip/hip_runtime.h>
#include <cstdint>
#include <cstddef>

constexpr int F_IN  = 512;
constexpr int D_EMB = 128;
constexpr int D_HID = 64;
constexpr int N_CLS = 32;

typedef __attribute__((ext_vector_type(8))) short short8;
typedef __attribute__((ext_vector_type(4))) float floatx4;

__device__ inline unsigned short f2bf(float f) {
  union { float f; uint32_t u; } v; v.f = f;
  uint32_t r = v.u + 0x7FFF + ((v.u >> 16) & 1);   // round-to-nearest-even
  return (unsigned short)(r >> 16);
}

// ---- W1 -> fragment-linear bf16: Wt2[kc8][ct][ks][lane] of short8 ----------
__global__ __launch_bounds__(256) void wt_kernel(
    const float* __restrict__ W1, short8* __restrict__ Wt2)
{
  int idx = blockIdx.x * 256 + threadIdx.x;     // 0..8191
  int kc8 = idx >> 10, lin = idx & 1023;
  int ct = lin >> 7, rem = lin & 127, ks = rem >> 6, ln = rem & 63;
  int col = ct * 16 + (ln & 15);
  int k0 = kc8 * 64 + ks * 32 + (ln >> 4) * 8;
  short8 s;
#pragma unroll
  for (int j = 0; j < 8; ++j)
    s[j] = (short)f2bf(W1[(size_t)(k0 + j) * D_EMB + col]);
  Wt2[idx] = s;
}

// ---- fused lin1 + conv1-mm: P = relu(X @ W1 + b1) @ Wc1 --------------------
// Phase 1: 64-row MFMA GEMM (X via swizzled LDS, 1-deep prefetch).
// Phase 2: relu(acc+b1) tile -> LDS (aliases dead X/W staging region),
// Wc1 staged in two 16KB halves (reg-prefetched), mm inner loop from LDS.
// H1 is never materialized in HBM (saves 102.4 MB round-trip + a launch).
// Numerics: identical MFMA chains + identical fp32 k-order => bit-identical
// to the old lin1_mfma + mm_kernel<128> pair.
__global__ __launch_bounds__(256) void l1c1_kernel(
    const float* __restrict__ X, const short8* __restrict__ Wt2,
    const float* __restrict__ b1, const float* __restrict__ Wc1,
    float* __restrict__ P, int n)
{
  __shared__ __align__(16) char smem[50176];
  short8* Xs = (short8*)smem;                      // 8 KB   (phase 1)
  short8* Ws = (short8*)(smem + 8192);             // 16 KB  (phase 1)
  float (*Hs)[132] = (float(*)[132])smem;          // 33792B (phase 2, aliases)
  float (*Wc)[64]  = (float(*)[64])(smem + 33792); // 16 KB  (phase 2)

  const int t = threadIdx.x;
  const int wave = t >> 6, lane = t & 63;
  const int quad = lane >> 4, mrow = lane & 15;
  const int node0 = blockIdx.x * 64;
  const int cw = wave * 2;                         // col-tile base (2 per wave)

  // phase-2 Wc1 half-0 prefetch: issued now, consumed after the K-loop
  float4 wp[4];
#pragma unroll
  for (int i = 0; i < 4; ++i) wp[i] = ((const float4*)Wc1)[i * 256 + t];

  // X staging assignment: g = t + i*256 (i<2); row = g>>3, col8 = g&7
  const float* sp[2];
  int soff[2];
#pragma unroll
  for (int i = 0; i < 2; ++i) {
    int g = t + i * 256;
    int row = g >> 3, col8 = g & 7;
    soff[i] = row * 128 + ((col8 * 16) ^ ((row & 7) << 4));
    int gr = node0 + row; if (gr >= n) gr = n - 1;
    sp[i] = &X[(size_t)gr * F_IN + col8 * 8];
  }

  floatx4 acc[4][2];
#pragma unroll
  for (int i = 0; i < 4; ++i)
#pragma unroll
    for (int j = 0; j < 2; ++j) acc[i][j] = (floatx4){0.f, 0.f, 0.f, 0.f};

  float4 xr[2][2];      // X prefetch regs (current tile)
  short8 wr[4];         // W prefetch regs (current tile)

#pragma unroll
  for (int i = 0; i < 2; ++i) {           // prologue: tile 0
    xr[i][0] = *(const float4*)sp[i];
    xr[i][1] = *(const float4*)(sp[i] + 4);
  }
#pragma unroll
  for (int i = 0; i < 4; ++i) wr[i] = Wt2[t + i * 256];

  for (int kc8 = 0; kc8 < 8; ++kc8) {
    short8 s8[2];
#pragma unroll
    for (int i = 0; i < 2; ++i) {
      s8[i][0] = (short)f2bf(xr[i][0].x); s8[i][1] = (short)f2bf(xr[i][0].y);
      s8[i][2] = (short)f2bf(xr[i][0].z); s8[i][3] = (short)f2bf(xr[i][0].w);
      s8[i][4] = (short)f2bf(xr[i][1].x); s8[i][5] = (short)f2bf(xr[i][1].y);
      s8[i][6] = (short)f2bf(xr[i][1].z); s8[i][7] = (short)f2bf(xr[i][1].w);
    }
    __syncthreads();                      // WAR: prev tile's compute done
#pragma unroll
    for (int i = 0; i < 2; ++i)
      *(short8*)((char*)Xs + soff[i]) = s8[i];
#pragma unroll
    for (int i = 0; i < 4; ++i)
      Ws[t + i * 256] = wr[i];
    __syncthreads();                      // tile visible

    if (kc8 < 7) {                        // issue NEXT tile's loads
#pragma unroll
      for (int i = 0; i < 2; ++i) {
        const float* p = sp[i] + (kc8 + 1) * 64;
        xr[i][0] = *(const float4*)p;
        xr[i][1] = *(const float4*)(p + 4);
      }
#pragma unroll
      for (int i = 0; i < 4; ++i)
        wr[i] = Wt2[(kc8 + 1) * 1024 + t + i * 256];
    }

#pragma unroll
    for (int ks = 0; ks < 2; ++ks) {
      short8 af[4], bf[2];
#pragma unroll
      for (int rt = 0; rt < 4; ++rt) {
        int row = rt * 16 + mrow;
        int byteoff = row * 128 + ((ks * 64 + quad * 16) ^ ((row & 7) << 4));
        af[rt] = *(const short8*)((const char*)Xs + byteoff);
      }
#pragma unroll
      for (int c = 0; c < 2; ++c)
        bf[c] = Ws[((cw + c) * 2 + ks) * 64 + lane];
#pragma unroll
      for (int rt = 0; rt < 4; ++rt)
#pragma unroll
        for (int c = 0; c < 2; ++c)
          acc[rt][c] = __builtin_amdgcn_mfma_f32_16x16x32_bf16(
              af[rt], bf[c], acc[rt][c], 0, 0, 0);
    }
  }

  // ---------------- phase 2: P-tile = relu(H1-tile) @ Wc1 -------------------
  __syncthreads();                        // all Xs/Ws reads complete (alias!)
#pragma unroll
  for (int ct = 0; ct < 2; ++ct) {
    int col = (cw + ct) * 16 + mrow;
    float b = b1[col];
#pragma unroll
    for (int rt = 0; rt < 4; ++rt)
#pragma unroll
      for (int r = 0; r < 4; ++r)
        Hs[rt * 16 + quad * 4 + r][col] = fmaxf(acc[rt][ct][r] + b, 0.f);
  }
#pragma unroll
  for (int i = 0; i < 4; ++i)             // Wc1 half 0 into LDS
    ((float4*)&Wc[0][0])[i * 256 + t] = wp[i];
  __syncthreads();

#pragma unroll
  for (int i = 0; i < 4; ++i)             // prefetch Wc1 half 1
    wp[i] = ((const float4*)Wc1)[1024 + i * 256 + t];

  const int rg = t >> 4, cg = t & 15;
  float acc2[4][4];
#pragma unroll
  for (int i = 0; i < 4; ++i)
#pragma unroll
    for (int j = 0; j < 4; ++j) acc2[i][j] = 0.f;

#pragma unroll 8
  for (int k = 0; k < 64; ++k) {          // k = 0..63
    float a[4] = {Hs[rg*4+0][k], Hs[rg*4+1][k], Hs[rg*4+2][k], Hs[rg*4+3][k]};
    float4 b = *(const float4*)&Wc[k][cg * 4];
#pragma unroll
    for (int i = 0; i < 4; ++i) {
      acc2[i][0] += a[i]*b.x; acc2[i][1] += a[i]*b.y;
      acc2[i][2] += a[i]*b.z; acc2[i][3] += a[i]*b.w;
    }
  }
  __syncthreads();
#pragma unroll
  for (int i = 0; i < 4; ++i)             // Wc1 half 1 into LDS
    ((float4*)&Wc[0][0])[i * 256 + t] = wp[i];
  __syncthreads();

#pragma unroll 8
  for (int k = 0; k < 64; ++k) {          // k = 64..127
    float a[4] = {Hs[rg*4+0][64+k], Hs[rg*4+1][64+k],
                  Hs[rg*4+2][64+k], Hs[rg*4+3][64+k]};
    float4 b = *(const float4*)&Wc[k][cg * 4];
#pragma unroll
    for (int i = 0; i < 4; ++i) {
      acc2[i][0] += a[i]*b.x; acc2[i][1] += a[i]*b.y;
      acc2[i][2] += a[i]*b.z; acc2[i][3] += a[i]*b.w;
    }
  }
#pragma unroll
  for (int i = 0; i < 4; ++i) {
    int gn = node0 + rg * 4 + i;
    if (gn < n) {
      float4 o = make_float4(acc2[i][0], acc2[i][1], acc2[i][2], acc2[i][3]);
      *(float4*)&P[(size_t)gn * 64 + cg * 4] = o;
    }
  }
}

// ======= fused gather + pre(relu,deg,bias) + matmul: Out = pre(agg(P)) @ W ==
__global__ __launch_bounds__(512) void gmm_kernel(
    const float* __restrict__ P, const int* __restrict__ offs,
    const int* __restrict__ adj, const int* __restrict__ deg,
    const float* __restrict__ bin, const float* __restrict__ W,
    float* __restrict__ Out, int n)
{
  __shared__ float Hs[64][68];
  __shared__ float Ws[64][64];
  const int t = threadIdx.x;
  const int wave = t >> 6, lane = t & 63;
  const int node0 = blockIdx.x * 64;

#pragma unroll
  for (int i = 0; i < 2; ++i) {
    int lin = t + i * 512;
    ((float4*)&Ws[0][0])[lin] = ((const float4*)W)[lin];
  }
  const float bb = bin[lane];

#pragma unroll 1
  for (int nd = 0; nd < 8; ++nd) {
    int ln = wave * 8 + nd;
    int node = node0 + ln;
    float v = 0.f;
    if (node < n) {
      int beg = offs[node], end = offs[node + 1];
      float a0 = 0.f, a1 = 0.f, a2 = 0.f, a3 = 0.f;
      int j = beg;
      while (j < end) {
        int m = min(end - j, 64);
        int idx = (lane < m) ? adj[j + lane] : 0;
        int q = 0;
        for (; q + 3 < m; q += 4) {
          int s0 = __shfl(idx, q, 64),     s1 = __shfl(idx, q + 1, 64);
          int s2 = __shfl(idx, q + 2, 64), s3 = __shfl(idx, q + 3, 64);
          a0 += P[(size_t)s0 * 64 + lane];
          a1 += P[(size_t)s1 * 64 + lane];
          a2 += P[(size_t)s2 * 64 + lane];
          a3 += P[(size_t)s3 * 64 + lane];
        }
        for (; q < m; ++q) {
          int s0 = __shfl(idx, q, 64);
          a0 += P[(size_t)s0 * 64 + lane];
        }
        j += m;
      }
      float rd = 1.f / fmaxf((float)deg[node], 1.f);
      v = fmaxf(((a0 + a2) + (a1 + a3)) * rd + bb, 0.f);
    }
    Hs[ln][lane] = v;
  }
  __syncthreads();

  const int rg = t >> 4, cg = t & 15;          // rg 0..31 -> 2 rows each
  float acc[2][4];
#pragma unroll
  for (int i = 0; i < 2; ++i)
#pragma unroll
    for (int j = 0; j < 4; ++j) acc[i][j] = 0.f;

#pragma unroll 8
  for (int k = 0; k < 64; ++k) {
    float a[2] = {Hs[rg * 2 + 0][k], Hs[rg * 2 + 1][k]};
    float4 b = *(const float4*)&Ws[k][cg * 4];
#pragma unroll
    for (int i = 0; i < 2; ++i) {
      acc[i][0] += a[i]*b.x; acc[i][1] += a[i]*b.y;
      acc[i][2] += a[i]*b.z; acc[i][3] += a[i]*b.w;
    }
  }
#pragma unroll
  for (int i = 0; i < 2; ++i) {
    int gn = node0 + rg * 2 + i;
    if (gn < n) {
      float4 o = make_float4(acc[i][0], acc[i][1], acc[i][2], acc[i][3]);
      *(float4*)&Out[(size_t)gn * 64 + cg * 4] = o;
    }
  }
}

// ======= fused gather3 + post3: H4 = relu(agg(P)/deg + bc3); stats ==========
__global__ __launch_bounds__(512) void gp_kernel(
    const float* __restrict__ P, const int* __restrict__ offs,
    const int* __restrict__ adj, const int* __restrict__ deg,
    const float* __restrict__ bc3, float* __restrict__ H4,
    float* __restrict__ stats, int n)
{
  const int t = threadIdx.x;
  const int wave = t >> 6, lane = t & 63;
  const int node0 = blockIdx.x * 64;
  const float bb = bc3[lane];
  float s = 0.f, s2 = 0.f;

#pragma unroll 1
  for (int nd = 0; nd < 8; ++nd) {
    int node = node0 + wave * 8 + nd;
    if (node >= n) break;
    int beg = offs[node], end = offs[node + 1];
    float a0 = 0.f, a1 = 0.f, a2 = 0.f, a3 = 0.f;
    int j = beg;
    while (j < end) {
      int m = min(end - j, 64);
      int idx = (lane < m) ? adj[j + lane] : 0;
      int q = 0;
      for (; q + 3 < m; q += 4) {
        int s0 = __shfl(idx, q, 64),      s1 = __shfl(idx, q + 1, 64);
        int s2i = __shfl(idx, q + 2, 64), s3 = __shfl(idx, q + 3, 64);
        a0 += P[(size_t)s0 * 64 + lane];
        a1 += P[(size_t)s1 * 64 + lane];
        a2 += P[(size_t)s2i * 64 + lane];
        a3 += P[(size_t)s3 * 64 + lane];
      }
      for (; q < m; ++q) {
        int s0 = __shfl(idx, q, 64);
        a0 += P[(size_t)s0 * 64 + lane];
      }
      j += m;
    }
    float rd = 1.f / fmaxf((float)deg[node], 1.f);
    float v = fmaxf(((a0 + a2) + (a1 + a3)) * rd + bb, 0.f);
    H4[(size_t)node * 64 + lane] = v;
    s += v; s2 += v * v;
  }

  __shared__ float red[2][8][64];
  red[0][wave][lane] = s; red[1][wave][lane] = s2;
  __syncthreads();
  if (t < 128) {
    int which = t >> 6, ff = t & 63;
    float a = 0.f;
#pragma unroll
    for (int w = 0; w < 8; ++w) a += red[which][w][ff];
    atomicAdd(&stats[which * 64 + ff], a);
  }
}

// ============== CSR build: bucketed, no global scatter ======================
__global__ __launch_bounds__(256) void hist_kernel(
    const int* __restrict__ dst, int* __restrict__ G,
    float* __restrict__ stats, int nE, int B, int NB)
{
  __shared__ int h[256];
  int blk = blockIdx.x, t = threadIdx.x;
  if (blk == 0 && t < 128) stats[t] = 0.f;     // folded stats memset
  h[t] = 0;
  __syncthreads();
  int base = blk * 8192;
  int lim = min(8192, nE - base);
  for (int i = t; i < lim; i += 256)
    atomicAdd(&h[dst[base + i] >> 9], 1);
  __syncthreads();
  if (t < NB) G[t * B + blk] = h[t];
}

__global__ __launch_bounds__(256) void scan1_kernel(
    const int* __restrict__ in, int* __restrict__ out,
    int* __restrict__ bsum, int n)
{
  __shared__ int sh[256];
  int t = threadIdx.x;
  int i = blockIdx.x * 256 + t;
  int c = (i < n) ? in[i] : 0;
  sh[t] = c;
  __syncthreads();
#pragma unroll
  for (int off = 1; off < 256; off <<= 1) {
    int v = 0;
    if (t >= off) v = sh[t - off];
    __syncthreads();
    if (t >= off) sh[t] += v;
    __syncthreads();
  }
  if (i < n) out[i] = sh[t] - c;
  if (t == 255) bsum[blockIdx.x] = sh[255];
}

__global__ __launch_bounds__(256) void scan2_kernel(int* __restrict__ bsum, int nb)
{
  __shared__ int sh[256];
  __shared__ int carry;
  int t = threadIdx.x;
  if (t == 0) carry = 0;
  __syncthreads();
  for (int base = 0; base < nb; base += 256) {
    int i = base + t;
    int v = (i < nb) ? bsum[i] : 0;
    sh[t] = v;
    __syncthreads();
#pragma unroll
    for (int off = 1; off < 256; off <<= 1) {
      int u = 0;
      if (t >= off) u = sh[t - off];
      __syncthreads();
      if (t >= off) sh[t] += u;
      __syncthreads();
    }
    int c0 = carry;
    int incl = sh[t], total = sh[255];
    if (i < nb) bsum[i] = c0 + incl - v;
    __syncthreads();
    if (t == 0) carry = c0 + total;
    __syncthreads();
  }
  if (t == 0) bsum[nb] = carry;
}

// scatter edges into bucket-major pair array; block-exclusive regions
__global__ __launch_bounds__(256) void scatter2_kernel(
    const int* __restrict__ src, const int* __restrict__ dst,
    const int* __restrict__ W, const int* __restrict__ bsum,
    int2* __restrict__ EP, int nE, int B, int NB)
{
  __shared__ int cur[256];
  int blk = blockIdx.x, t = threadIdx.x;
  if (t < NB) {
    int gi = t * B + blk;
    cur[t] = W[gi] + bsum[gi >> 8];
  }
  __syncthreads();
  int base = blk * 8192;
  int lim = min(8192, nE - base);
  for (int i = t; i < lim; i += 256) {
    int s = src[base + i], d = dst[base + i];
    int slot = atomicAdd(&cur[d >> 9], 1);
    EP[slot] = make_int2(s, d);
  }
}

// per-bucket: cnt/offs from LDS hist+scan; adj fill in block-local window
__global__ __launch_bounds__(256) void fillc_kernel(
    const int2* __restrict__ EP, const int* __restrict__ W,
    const int* __restrict__ bsum,
    int* __restrict__ cnt, int* __restrict__ offs, int* __restrict__ adj,
    int n, int nE, int B, int NB)
{
  __shared__ int h[512];
  int b = blockIdx.x, t = threadIdx.x;
  int g0i = b * B;
  int segStart = W[g0i] + bsum[g0i >> 8];
  int segEnd = (b == NB - 1) ? nE : (W[g0i + B] + bsum[(g0i + B) >> 8]);
  int nodeBase = b << 9;

  h[t] = 0; h[t + 256] = 0;
  __syncthreads();
  for (int i = segStart + t; i < segEnd; i += 256)
    atomicAdd(&h[EP[i].y - nodeBase], 1);
  __syncthreads();
  int c0 = h[t], c1 = h[t + 256];
#pragma unroll
  for (int off = 1; off < 512; off <<= 1) {
    int a = (t >= off) ? h[t - off] : 0;
    int bb = (t + 256 >= off) ? h[t + 256 - off] : 0;
    __syncthreads();
    h[t] += a; h[t + 256] += bb;
    __syncthreads();
  }
  int e0 = h[t] - c0, e1 = h[t + 256] - c1;   // exclusive
  int g0 = nodeBase + t, g1 = nodeBase + t + 256;
  if (g0 < n) { cnt[g0] = c0; offs[g0] = segStart + e0; }
  if (g1 < n) { cnt[g1] = c1; offs[g1] = segStart + e1; }
  if (b == 0 && t == 0) offs[n] = nE;
  __syncthreads();
  h[t] = e0; h[t + 256] = e1;                 // cursors
  __syncthreads();
  for (int i = segStart + t; i < segEnd; i += 256) {
    int2 p = EP[i];
    int slot = atomicAdd(&h[p.y - nodeBase], 1);
    adj[segStart + slot] = p.x;
  }
}

// ---- fold batchnorm into W2 ------------------------------------------------
__global__ __launch_bounds__(256) void fold_kernel(
    const float* __restrict__ stats, const float* __restrict__ gamma,
    const float* __restrict__ beta, const float* __restrict__ W2,
    const float* __restrict__ b2, float* __restrict__ W2f,
    float* __restrict__ b2f, int n)
{
  __shared__ float rsg[64], corr[64];
  int t = threadIdx.x;
  if (t < 64) {
    float m = stats[t] / (float)n;
    float var = stats[64 + t] / (float)n - m * m;
    float rs = rsqrtf(var + 1e-5f);
    float g = gamma[t] * rs;
    rsg[t] = g;
    corr[t] = beta[t] - m * g;
  }
  __syncthreads();
#pragma unroll
  for (int i = 0; i < 8; ++i) {
    int lin = t + i * 256;
    int k = lin >> 5;
    W2f[lin] = rsg[k] * W2[lin];
  }
  if (t < 32) {
    float a = b2[t];
    for (int k = 0; k < 64; ++k) a += corr[k] * W2[k * 32 + t];
    b2f[t] = a;
  }
}

// ---- final: out = relu(H4 @ W2f + b2f) @ W3 + b3 ---------------------------
__global__ __launch_bounds__(256) void final_kernel(
    const float* __restrict__ H4, const float* __restrict__ W2f,
    const float* __restrict__ b2f, const float* __restrict__ W3,
    const float* __restrict__ b3, float* __restrict__ Out, int n)
{
  __shared__ float Hs[64][68];
  __shared__ float W2s[64][32];
  __shared__ float W3s[32][32];
  __shared__ float Us[64][36];
  __shared__ float b2s[32], b3s[32];
  const int t = threadIdx.x;
  const int node0 = blockIdx.x * 64;

#pragma unroll
  for (int i = 0; i < 4; ++i) {
    int lin = t + i * 256;
    int node = lin >> 4, kq = lin & 15;
    float4 v = make_float4(0.f, 0.f, 0.f, 0.f);
    if (node0 + node < n)
      v = *(const float4*)&H4[(size_t)(node0 + node) * 64 + kq * 4];
    *(float4*)&Hs[node][kq * 4] = v;
  }
#pragma unroll
  for (int i = 0; i < 2; ++i) {
    int lin = t + i * 256;
    ((float4*)&W2s[0][0])[lin] = ((const float4*)W2f)[lin];
  }
  ((float4*)&W3s[0][0])[t & 255] = ((const float4*)W3)[t & 255];
  if (t < 32) { b2s[t] = b2f[t]; b3s[t] = b3[t]; }
  __syncthreads();

  const int rg = t >> 4, cg = t & 15;
  float acc[4][2] = {{0.f,0.f},{0.f,0.f},{0.f,0.f},{0.f,0.f}};
#pragma unroll 8
  for (int k = 0; k < 64; ++k) {
    float a[4] = {Hs[rg*4+0][k], Hs[rg*4+1][k], Hs[rg*4+2][k], Hs[rg*4+3][k]};
    float w0 = W2s[k][cg*2], w1 = W2s[k][cg*2+1];
#pragma unroll
    for (int i = 0; i < 4; ++i) { acc[i][0] += a[i]*w0; acc[i][1] += a[i]*w1; }
  }
#pragma unroll
  for (int i = 0; i < 4; ++i) {
    Us[rg*4+i][cg*2+0] = fmaxf(acc[i][0] + b2s[cg*2+0], 0.f);
    Us[rg*4+i][cg*2+1] = fmaxf(acc[i][1] + b2s[cg*2+1], 0.f);
  }
  __syncthreads();

  float acc2[4][2] = {{0.f,0.f},{0.f,0.f},{0.f,0.f},{0.f,0.f}};
#pragma unroll
  for (int k = 0; k < 32; ++k) {
    float a[4] = {Us[rg*4+0][k], Us[rg*4+1][k], Us[rg*4+2][k], Us[rg*4+3][k]};
    float w0 = W3s[k][cg*2], w1 = W3s[k][cg*2+1];
#pragma unroll
    for (int i = 0; i < 4; ++i) { acc2[i][0] += a[i]*w0; acc2[i][1] += a[i]*w1; }
  }
  float (*Os)[36] = (float(*)[36])Hs;
#pragma unroll
  for (int i = 0; i < 4; ++i) {
    Os[rg*4+i][cg*2+0] = acc2[i][0] + b3s[cg*2+0];
    Os[rg*4+i][cg*2+1] = acc2[i][1] + b3s[cg*2+1];
  }
  __syncthreads();
#pragma unroll
  for (int i = 0; i < 2; ++i) {
    int lin = t + i * 256;
    int node = lin >> 3, c4 = lin & 7;
    if (node0 + node < n)
      *(float4*)&Out[(size_t)(node0 + node) * 32 + c4 * 4] =
          *(float4*)&Os[node][c4 * 4];
  }
}

// ---------------------------------------------------------------------------
extern "C" void kernel_launch(void* const* d_in, const int* in_sizes, int n_in,
                              void* d_out, int out_size, void* d_ws, size_t ws_size,
                              hipStream_t stream)
{
  const float* X     = (const float*)d_in[0];
  const float* W1    = (const float*)d_in[1];
  const float* b1    = (const float*)d_in[2];
  const float* Wc1   = (const float*)d_in[3];
  const float* bc1   = (const float*)d_in[4];
  const float* Wc2   = (const float*)d_in[5];
  const float* bc2   = (const float*)d_in[6];
  const float* Wc3   = (const float*)d_in[7];
  const float* bc3   = (const float*)d_in[8];
  const float* gamma = (const float*)d_in[9];
  const float* beta  = (const float*)d_in[10];
  const float* W2    = (const float*)d_in[11];
  const float* b2    = (const float*)d_in[12];
  const float* W3    = (const float*)d_in[13];
  const float* b3    = (const float*)d_in[14];
  const int*   ei    = (const int*)d_in[15];

  const int n  = in_sizes[0] / F_IN;
  const int nE = in_sizes[15] / 2;
  const int* src  = ei;
  const int* dstv = ei + nE;

  const int NB = (n + 511) >> 9;          // buckets of 512 nodes
  const int B  = (nE + 8191) >> 13;       // chunks of 8192 edges
  const int NG = NB * B;
  const int nbG = (NG + 255) / 256;

  float* ws    = (float*)d_ws;
  float* Pa    = ws;                                   // n*64 fp32 (ping)
  float* Pb    = Pa + (size_t)n * D_HID;               // n*64 fp32 (pong)
  float* stats = Pb + (size_t)n * D_HID;               // 128
  float* W2f   = stats + 128;                          // 2048
  float* b2f   = W2f + 2048;                           // 32
  int*   cnt   = (int*)(b2f + 32);                     // n
  int*   offs  = cnt + n;                              // n+1
  int*   G     = offs + n + 1;                         // NG
  int*   W     = G + NG;                               // NG+1
  int*   bsum  = W + NG + 1;                           // nbG+1
  int*   adj   = bsum + nbG + 1;                       // nE
  uintptr_t epAddr = ((uintptr_t)(adj + nE) + 7) & ~(uintptr_t)7;
  int2*  EP    = (int2*)epAddr;                        // nE pairs
  short8* Wt2  = (short8*)(EP + nE);                   // 128KB
  float* H4    = Pb;                                   // reuse Pb (dead after conv3)

  const int nb  = (n + 63) / 64;

  // W1 -> fragment-linear bf16, then fused lin1+conv1 (H1 never hits HBM)
  wt_kernel<<<32, 256, 0, stream>>>(W1, Wt2);
  l1c1_kernel<<<nb, 256, 0, stream>>>(X, Wt2, b1, Wc1, Pa, n);

  // CSR build (bucketed, no global scatter; scan3 folded into read sites)
  hist_kernel<<<B, 256, 0, stream>>>(dstv, G, stats, nE, B, NB);
  scan1_kernel<<<nbG, 256, 0, stream>>>(G, W, bsum, NG);
  scan2_kernel<<<1, 256, 0, stream>>>(bsum, nbG);
  scatter2_kernel<<<B, 256, 0, stream>>>(src, dstv, W, bsum, EP, nE, B, NB);
  fillc_kernel<<<NB, 256, 0, stream>>>(EP, W, bsum, cnt, offs, adj, n, nE, B, NB);

  // conv2: Pb = relu(agg(Pa)/deg + bc1) @ Wc2   (fused gather+pre+mm)
  gmm_kernel<<<nb, 512, 0, stream>>>(Pa, offs, adj, cnt, bc1, Wc2, Pb, n);

  // conv3: Pa = relu(agg(Pb)/deg + bc2) @ Wc3
  gmm_kernel<<<nb, 512, 0, stream>>>(Pb, offs, adj, cnt, bc2, Wc3, Pa, n);

  // conv3 epilogue: H4 = relu(agg(Pa)/deg + bc3); batch stats
  gp_kernel<<<nb, 512, 0, stream>>>(Pa, offs, adj, cnt, bc3, H4, stats, n);

  // fold batchnorm into W2, then fused lin2+lin3
  fold_kernel<<<1, 256, 0, stream>>>(stats, gamma, beta, W2, b2, W2f, b2f, n);
  final_kernel<<<nb, 256, 0, stream>>>(H4, W2f, b2f, W3, b3, (float*)d_out, n);
}

// Round 5
// 631.995 us; speedup vs baseline: 1.1553x; 1.0408x over previous
//
#include <hip/hip_runtime.h>
#include <cstdint>
#include <cstddef>

constexpr int F_IN  = 512;
constexpr int D_EMB = 128;
constexpr int D_HID = 64;
constexpr int N_CLS = 32;

typedef __attribute__((ext_vector_type(8))) short short8;
typedef __attribute__((ext_vector_type(4))) float floatx4;

__device__ inline unsigned short f2bf(float f) {
  union { float f; uint32_t u; } v; v.f = f;
  uint32_t r = v.u + 0x7FFF + ((v.u >> 16) & 1);   // round-to-nearest-even
  return (unsigned short)(r >> 16);
}

// ---- W1 -> fragment-linear bf16: Wt2[kc8][ct][ks][lane] of short8 ----------
__global__ __launch_bounds__(256) void wt_kernel(
    const float* __restrict__ W1, short8* __restrict__ Wt2)
{
  int idx = blockIdx.x * 256 + threadIdx.x;     // 0..8191
  int kc8 = idx >> 10, lin = idx & 1023;
  int ct = lin >> 7, rem = lin & 127, ks = rem >> 6, ln = rem & 63;
  int col = ct * 16 + (ln & 15);
  int k0 = kc8 * 64 + ks * 32 + (ln >> 4) * 8;
  short8 s;
#pragma unroll
  for (int j = 0; j < 8; ++j)
    s[j] = (short)f2bf(W1[(size_t)(k0 + j) * D_EMB + col]);
  Wt2[idx] = s;
}

// ---- fused lin1 + conv1-mm: P = relu(X @ W1 + b1) @ Wc1 --------------------
// Phase 1: 64-row MFMA GEMM, X via swizzled LDS, 2-DEEP A/B register
// pipeline: tile k's global loads issue during tile k-2's compute, so each
// load has a full K-step (~600+cy) of latency coverage (was 1-deep = stall).
// Phase 2: relu(acc+b1) tile -> LDS (aliases staging), mm from LDS.
__global__ __launch_bounds__(256) void l1c1_kernel(
    const float* __restrict__ X, const short8* __restrict__ Wt2,
    const float* __restrict__ b1, const float* __restrict__ Wc1,
    float* __restrict__ P, int n)
{
  __shared__ __align__(16) char smem[50176];
  short8* Xs = (short8*)smem;                      // 8 KB   (phase 1)
  short8* Ws = (short8*)(smem + 8192);             // 16 KB  (phase 1)
  float (*Hs)[132] = (float(*)[132])smem;          // 33792B (phase 2, aliases)
  float (*Wc)[64]  = (float(*)[64])(smem + 33792); // 16 KB  (phase 2)

  const int t = threadIdx.x;
  const int wave = t >> 6, lane = t & 63;
  const int quad = lane >> 4, mrow = lane & 15;
  const int node0 = blockIdx.x * 64;
  const int cw = wave * 2;                         // col-tile base (2 per wave)

  // phase-2 Wc1 half-0 prefetch: issued now, consumed after the K-loop
  float4 wp[4];
#pragma unroll
  for (int i = 0; i < 4; ++i) wp[i] = ((const float4*)Wc1)[i * 256 + t];

  // X staging assignment: g = t + i*256 (i<2); row = g>>3, col8 = g&7
  const float* sp[2];
  int soff[2];
#pragma unroll
  for (int i = 0; i < 2; ++i) {
    int g = t + i * 256;
    int row = g >> 3, col8 = g & 7;
    soff[i] = row * 128 + ((col8 * 16) ^ ((row & 7) << 4));
    int gr = node0 + row; if (gr >= n) gr = n - 1;
    sp[i] = &X[(size_t)gr * F_IN + col8 * 8];
  }

  floatx4 acc[4][2];
#pragma unroll
  for (int i = 0; i < 4; ++i)
#pragma unroll
    for (int j = 0; j < 2; ++j) acc[i][j] = (floatx4){0.f, 0.f, 0.f, 0.f};

  float4 xrA[2][2], xrB[2][2];    // 2-deep X prefetch (tiles k, k+1)
  short8 wrA[4], wrB[4];          // 2-deep W prefetch

#pragma unroll
  for (int i = 0; i < 2; ++i) {   // prologue: tiles 0 and 1
    xrA[i][0] = *(const float4*)sp[i];
    xrA[i][1] = *(const float4*)(sp[i] + 4);
    xrB[i][0] = *(const float4*)(sp[i] + 64);
    xrB[i][1] = *(const float4*)(sp[i] + 68);
  }
#pragma unroll
  for (int i = 0; i < 4; ++i) {
    wrA[i] = Wt2[t + i * 256];
    wrB[i] = Wt2[1024 + t + i * 256];
  }

  auto substep = [&](float4 (&xr)[2][2], short8 (&wr)[4], int knext) {
    short8 s8[2];
#pragma unroll
    for (int i = 0; i < 2; ++i) {
      s8[i][0] = (short)f2bf(xr[i][0].x); s8[i][1] = (short)f2bf(xr[i][0].y);
      s8[i][2] = (short)f2bf(xr[i][0].z); s8[i][3] = (short)f2bf(xr[i][0].w);
      s8[i][4] = (short)f2bf(xr[i][1].x); s8[i][5] = (short)f2bf(xr[i][1].y);
      s8[i][6] = (short)f2bf(xr[i][1].z); s8[i][7] = (short)f2bf(xr[i][1].w);
    }
    __syncthreads();                      // WAR: prev tile's compute done
#pragma unroll
    for (int i = 0; i < 2; ++i)
      *(short8*)((char*)Xs + soff[i]) = s8[i];
#pragma unroll
    for (int i = 0; i < 4; ++i)
      Ws[t + i * 256] = wr[i];
    __syncthreads();                      // tile visible

    if (knext < 8) {                      // refill this buffer, 2 tiles ahead
#pragma unroll
      for (int i = 0; i < 2; ++i) {
        const float* p = sp[i] + knext * 64;
        xr[i][0] = *(const float4*)p;
        xr[i][1] = *(const float4*)(p + 4);
      }
#pragma unroll
      for (int i = 0; i < 4; ++i)
        wr[i] = Wt2[knext * 1024 + t + i * 256];
    }

#pragma unroll
    for (int ks = 0; ks < 2; ++ks) {
      short8 af[4], bf[2];
#pragma unroll
      for (int rt = 0; rt < 4; ++rt) {
        int row = rt * 16 + mrow;
        int byteoff = row * 128 + ((ks * 64 + quad * 16) ^ ((row & 7) << 4));
        af[rt] = *(const short8*)((const char*)Xs + byteoff);
      }
#pragma unroll
      for (int c = 0; c < 2; ++c)
        bf[c] = Ws[((cw + c) * 2 + ks) * 64 + lane];
#pragma unroll
      for (int rt = 0; rt < 4; ++rt)
#pragma unroll
        for (int c = 0; c < 2; ++c)
          acc[rt][c] = __builtin_amdgcn_mfma_f32_16x16x32_bf16(
              af[rt], bf[c], acc[rt][c], 0, 0, 0);
    }
  };

#pragma unroll 1
  for (int kc8 = 0; kc8 < 8; kc8 += 2) {
    substep(xrA, wrA, kc8 + 2);
    substep(xrB, wrB, kc8 + 3);
  }

  // ---------------- phase 2: P-tile = relu(H1-tile) @ Wc1 -------------------
  __syncthreads();                        // all Xs/Ws reads complete (alias!)
#pragma unroll
  for (int ct = 0; ct < 2; ++ct) {
    int col = (cw + ct) * 16 + mrow;
    float b = b1[col];
#pragma unroll
    for (int rt = 0; rt < 4; ++rt)
#pragma unroll
      for (int r = 0; r < 4; ++r)
        Hs[rt * 16 + quad * 4 + r][col] = fmaxf(acc[rt][ct][r] + b, 0.f);
  }
#pragma unroll
  for (int i = 0; i < 4; ++i)             // Wc1 half 0 into LDS
    ((float4*)&Wc[0][0])[i * 256 + t] = wp[i];
  __syncthreads();

#pragma unroll
  for (int i = 0; i < 4; ++i)             // prefetch Wc1 half 1
    wp[i] = ((const float4*)Wc1)[1024 + i * 256 + t];

  const int rg = t >> 4, cg = t & 15;
  float acc2[4][4];
#pragma unroll
  for (int i = 0; i < 4; ++i)
#pragma unroll
    for (int j = 0; j < 4; ++j) acc2[i][j] = 0.f;

#pragma unroll 8
  for (int k = 0; k < 64; ++k) {          // k = 0..63
    float a[4] = {Hs[rg*4+0][k], Hs[rg*4+1][k], Hs[rg*4+2][k], Hs[rg*4+3][k]};
    float4 b = *(const float4*)&Wc[k][cg * 4];
#pragma unroll
    for (int i = 0; i < 4; ++i) {
      acc2[i][0] += a[i]*b.x; acc2[i][1] += a[i]*b.y;
      acc2[i][2] += a[i]*b.z; acc2[i][3] += a[i]*b.w;
    }
  }
  __syncthreads();
#pragma unroll
  for (int i = 0; i < 4; ++i)             // Wc1 half 1 into LDS
    ((float4*)&Wc[0][0])[i * 256 + t] = wp[i];
  __syncthreads();

#pragma unroll 8
  for (int k = 0; k < 64; ++k) {          // k = 64..127
    float a[4] = {Hs[rg*4+0][64+k], Hs[rg*4+1][64+k],
                  Hs[rg*4+2][64+k], Hs[rg*4+3][64+k]};
    float4 b = *(const float4*)&Wc[k][cg * 4];
#pragma unroll
    for (int i = 0; i < 4; ++i) {
      acc2[i][0] += a[i]*b.x; acc2[i][1] += a[i]*b.y;
      acc2[i][2] += a[i]*b.z; acc2[i][3] += a[i]*b.w;
    }
  }
#pragma unroll
  for (int i = 0; i < 4; ++i) {
    int gn = node0 + rg * 4 + i;
    if (gn < n) {
      float4 o = make_float4(acc2[i][0], acc2[i][1], acc2[i][2], acc2[i][3]);
      *(float4*)&P[(size_t)gn * 64 + cg * 4] = o;
    }
  }
}

// ---- scalar-indexed 8-deep gather body (shared by gmm/gp) ------------------
// beg/end forced to SGPR via readfirstlane (wave-uniform) so adj[] reads
// compile to s_load (no ds_bpermute chain); 8 accumulators keep 8 row loads
// (2 KB/wave) in flight. Branchless tail: indices clamp to end-1 (dup row =
// L1 hit), contributions predicated to 0 (exact).
__device__ inline float gather_row(
    const float* __restrict__ P, const int* __restrict__ adj,
    int beg, int end, int lane)
{
  float a0=0.f,a1=0.f,a2=0.f,a3=0.f,a4=0.f,a5=0.f,a6=0.f,a7=0.f;
  int j = beg;
  for (; j + 8 <= end; j += 8) {
    int s0=adj[j+0], s1=adj[j+1], s2=adj[j+2], s3=adj[j+3];
    int s4=adj[j+4], s5=adj[j+5], s6=adj[j+6], s7=adj[j+7];
    a0 += P[(size_t)s0 * 64 + lane];
    a1 += P[(size_t)s1 * 64 + lane];
    a2 += P[(size_t)s2 * 64 + lane];
    a3 += P[(size_t)s3 * 64 + lane];
    a4 += P[(size_t)s4 * 64 + lane];
    a5 += P[(size_t)s5 * 64 + lane];
    a6 += P[(size_t)s6 * 64 + lane];
    a7 += P[(size_t)s7 * 64 + lane];
  }
  if (j < end) {                    // tail: 1..7 elements
    int e1 = end - 1;
    int s0 = adj[j];
    int s1 = adj[min(j+1,e1)], s2 = adj[min(j+2,e1)], s3 = adj[min(j+3,e1)];
    int s4 = adj[min(j+4,e1)], s5 = adj[min(j+5,e1)], s6 = adj[min(j+6,e1)];
    float v0 = P[(size_t)s0 * 64 + lane];
    float v1 = P[(size_t)s1 * 64 + lane];
    float v2 = P[(size_t)s2 * 64 + lane];
    float v3 = P[(size_t)s3 * 64 + lane];
    float v4 = P[(size_t)s4 * 64 + lane];
    float v5 = P[(size_t)s5 * 64 + lane];
    float v6 = P[(size_t)s6 * 64 + lane];
    a0 += v0;
    a1 += (j+1 < end) ? v1 : 0.f;
    a2 += (j+2 < end) ? v2 : 0.f;
    a3 += (j+3 < end) ? v3 : 0.f;
    a4 += (j+4 < end) ? v4 : 0.f;
    a5 += (j+5 < end) ? v5 : 0.f;
    a6 += (j+6 < end) ? v6 : 0.f;
  }
  return ((a0+a1)+(a2+a3))+((a4+a5)+(a6+a7));
}

// ======= fused gather + pre(relu,deg,bias) + matmul: Out = pre(agg(P)) @ W ==
__global__ __launch_bounds__(512) void gmm_kernel(
    const float* __restrict__ P, const int* __restrict__ offs,
    const int* __restrict__ adj, const int* __restrict__ deg,
    const float* __restrict__ bin, const float* __restrict__ W,
    float* __restrict__ Out, int n)
{
  __shared__ float Hs[64][68];
  __shared__ float Ws[64][64];
  const int t = threadIdx.x;
  const int wave = t >> 6, lane = t & 63;
  const int node0 = blockIdx.x * 64;

#pragma unroll
  for (int i = 0; i < 2; ++i) {
    int lin = t + i * 512;
    ((float4*)&Ws[0][0])[lin] = ((const float4*)W)[lin];
  }
  const float bb = bin[lane];

#pragma unroll 1
  for (int nd = 0; nd < 8; ++nd) {
    int ln = wave * 8 + nd;
    int node = node0 + ln;
    float v = 0.f;
    if (node < n) {
      int beg = __builtin_amdgcn_readfirstlane(offs[node]);
      int end = __builtin_amdgcn_readfirstlane(offs[node + 1]);
      float s = gather_row(P, adj, beg, end, lane);
      float rd = 1.f / fmaxf((float)deg[node], 1.f);
      v = fmaxf(s * rd + bb, 0.f);
    }
    Hs[ln][lane] = v;
  }
  __syncthreads();

  const int rg = t >> 4, cg = t & 15;          // rg 0..31 -> 2 rows each
  float acc[2][4];
#pragma unroll
  for (int i = 0; i < 2; ++i)
#pragma unroll
    for (int j = 0; j < 4; ++j) acc[i][j] = 0.f;

#pragma unroll 8
  for (int k = 0; k < 64; ++k) {
    float a[2] = {Hs[rg * 2 + 0][k], Hs[rg * 2 + 1][k]};
    float4 b = *(const float4*)&Ws[k][cg * 4];
#pragma unroll
    for (int i = 0; i < 2; ++i) {
      acc[i][0] += a[i]*b.x; acc[i][1] += a[i]*b.y;
      acc[i][2] += a[i]*b.z; acc[i][3] += a[i]*b.w;
    }
  }
#pragma unroll
  for (int i = 0; i < 2; ++i) {
    int gn = node0 + rg * 2 + i;
    if (gn < n) {
      float4 o = make_float4(acc[i][0], acc[i][1], acc[i][2], acc[i][3]);
      *(float4*)&Out[(size_t)gn * 64 + cg * 4] = o;
    }
  }
}

// ======= fused gather3 + post3: H4 = relu(agg(P)/deg + bc3); stats ==========
__global__ __launch_bounds__(512) void gp_kernel(
    const float* __restrict__ P, const int* __restrict__ offs,
    const int* __restrict__ adj, const int* __restrict__ deg,
    const float* __restrict__ bc3, float* __restrict__ H4,
    float* __restrict__ stats, int n)
{
  const int t = threadIdx.x;
  const int wave = t >> 6, lane = t & 63;
  const int node0 = blockIdx.x * 64;
  const float bb = bc3[lane];
  float s = 0.f, s2 = 0.f;

#pragma unroll 1
  for (int nd = 0; nd < 8; ++nd) {
    int node = node0 + wave * 8 + nd;
    if (node >= n) break;
    int beg = __builtin_amdgcn_readfirstlane(offs[node]);
    int end = __builtin_amdgcn_readfirstlane(offs[node + 1]);
    float a = gather_row(P, adj, beg, end, lane);
    float rd = 1.f / fmaxf((float)deg[node], 1.f);
    float v = fmaxf(a * rd + bb, 0.f);
    H4[(size_t)node * 64 + lane] = v;
    s += v; s2 += v * v;
  }

  __shared__ float red[2][8][64];
  red[0][wave][lane] = s; red[1][wave][lane] = s2;
  __syncthreads();
  if (t < 128) {
    int which = t >> 6, ff = t & 63;
    float a = 0.f;
#pragma unroll
    for (int w = 0; w < 8; ++w) a += red[which][w][ff];
    atomicAdd(&stats[which * 64 + ff], a);
  }
}

// ============== CSR build: bucketed, no global scatter ======================
__global__ __launch_bounds__(256) void hist_kernel(
    const int* __restrict__ dst, int* __restrict__ G,
    float* __restrict__ stats, int nE, int B, int NB)
{
  __shared__ int h[256];
  int blk = blockIdx.x, t = threadIdx.x;
  if (blk == 0 && t < 128) stats[t] = 0.f;     // folded stats memset
  h[t] = 0;
  __syncthreads();
  int base = blk * 8192;
  int lim = min(8192, nE - base);
  for (int i = t; i < lim; i += 256)
    atomicAdd(&h[dst[base + i] >> 9], 1);
  __syncthreads();
  if (t < NB) G[t * B + blk] = h[t];
}

__global__ __launch_bounds__(256) void scan1_kernel(
    const int* __restrict__ in, int* __restrict__ out,
    int* __restrict__ bsum, int n)
{
  __shared__ int sh[256];
  int t = threadIdx.x;
  int i = blockIdx.x * 256 + t;
  int c = (i < n) ? in[i] : 0;
  sh[t] = c;
  __syncthreads();
#pragma unroll
  for (int off = 1; off < 256; off <<= 1) {
    int v = 0;
    if (t >= off) v = sh[t - off];
    __syncthreads();
    if (t >= off) sh[t] += v;
    __syncthreads();
  }
  if (i < n) out[i] = sh[t] - c;
  if (t == 255) bsum[blockIdx.x] = sh[255];
}

__global__ __launch_bounds__(256) void scan2_kernel(int* __restrict__ bsum, int nb)
{
  __shared__ int sh[256];
  __shared__ int carry;
  int t = threadIdx.x;
  if (t == 0) carry = 0;
  __syncthreads();
  for (int base = 0; base < nb; base += 256) {
    int i = base + t;
    int v = (i < nb) ? bsum[i] : 0;
    sh[t] = v;
    __syncthreads();
#pragma unroll
    for (int off = 1; off < 256; off <<= 1) {
      int u = 0;
      if (t >= off) u = sh[t - off];
      __syncthreads();
      if (t >= off) sh[t] += u;
      __syncthreads();
    }
    int c0 = carry;
    int incl = sh[t], total = sh[255];
    if (i < nb) bsum[i] = c0 + incl - v;
    __syncthreads();
    if (t == 0) carry = c0 + total;
    __syncthreads();
  }
  if (t == 0) bsum[nb] = carry;
}

// scatter edges into bucket-major pair array; block-exclusive regions
__global__ __launch_bounds__(256) void scatter2_kernel(
    const int* __restrict__ src, const int* __restrict__ dst,
    const int* __restrict__ W, const int* __restrict__ bsum,
    int2* __restrict__ EP, int nE, int B, int NB)
{
  __shared__ int cur[256];
  int blk = blockIdx.x, t = threadIdx.x;
  if (t < NB) {
    int gi = t * B + blk;
    cur[t] = W[gi] + bsum[gi >> 8];
  }
  __syncthreads();
  int base = blk * 8192;
  int lim = min(8192, nE - base);
  for (int i = t; i < lim; i += 256) {
    int s = src[base + i], d = dst[base + i];
    int slot = atomicAdd(&cur[d >> 9], 1);
    EP[slot] = make_int2(s, d);
  }
}

// per-bucket: cnt/offs from LDS hist+scan; adj fill in block-local window
__global__ __launch_bounds__(256) void fillc_kernel(
    const int2* __restrict__ EP, const int* __restrict__ W,
    const int* __restrict__ bsum,
    int* __restrict__ cnt, int* __restrict__ offs, int* __restrict__ adj,
    int n, int nE, int B, int NB)
{
  __shared__ int h[512];
  int b = blockIdx.x, t = threadIdx.x;
  int g0i = b * B;
  int segStart = W[g0i] + bsum[g0i >> 8];
  int segEnd = (b == NB - 1) ? nE : (W[g0i + B] + bsum[(g0i + B) >> 8]);
  int nodeBase = b << 9;

  h[t] = 0; h[t + 256] = 0;
  __syncthreads();
  for (int i = segStart + t; i < segEnd; i += 256)
    atomicAdd(&h[EP[i].y - nodeBase], 1);
  __syncthreads();
  int c0 = h[t], c1 = h[t + 256];
#pragma unroll
  for (int off = 1; off < 512; off <<= 1) {
    int a = (t >= off) ? h[t - off] : 0;
    int bb = (t + 256 >= off) ? h[t + 256 - off] : 0;
    __syncthreads();
    h[t] += a; h[t + 256] += bb;
    __syncthreads();
  }
  int e0 = h[t] - c0, e1 = h[t + 256] - c1;   // exclusive
  int g0 = nodeBase + t, g1 = nodeBase + t + 256;
  if (g0 < n) { cnt[g0] = c0; offs[g0] = segStart + e0; }
  if (g1 < n) { cnt[g1] = c1; offs[g1] = segStart + e1; }
  if (b == 0 && t == 0) offs[n] = nE;
  __syncthreads();
  h[t] = e0; h[t + 256] = e1;                 // cursors
  __syncthreads();
  for (int i = segStart + t; i < segEnd; i += 256) {
    int2 p = EP[i];
    int slot = atomicAdd(&h[p.y - nodeBase], 1);
    adj[segStart + slot] = p.x;
  }
}

// ---- fold batchnorm into W2 ------------------------------------------------
__global__ __launch_bounds__(256) void fold_kernel(
    const float* __restrict__ stats, const float* __restrict__ gamma,
    const float* __restrict__ beta, const float* __restrict__ W2,
    const float* __restrict__ b2, float* __restrict__ W2f,
    float* __restrict__ b2f, int n)
{
  __shared__ float rsg[64], corr[64];
  int t = threadIdx.x;
  if (t < 64) {
    float m = stats[t] / (float)n;
    float var = stats[64 + t] / (float)n - m * m;
    float rs = rsqrtf(var + 1e-5f);
    float g = gamma[t] * rs;
    rsg[t] = g;
    corr[t] = beta[t] - m * g;
  }
  __syncthreads();
#pragma unroll
  for (int i = 0; i < 8; ++i) {
    int lin = t + i * 256;
    int k = lin >> 5;
    W2f[lin] = rsg[k] * W2[lin];
  }
  if (t < 32) {
    float a = b2[t];
    for (int k = 0; k < 64; ++k) a += corr[k] * W2[k * 32 + t];
    b2f[t] = a;
  }
}

// ---- final: out = relu(H4 @ W2f + b2f) @ W3 + b3 ---------------------------
__global__ __launch_bounds__(256) void final_kernel(
    const float* __restrict__ H4, const float* __restrict__ W2f,
    const float* __restrict__ b2f, const float* __restrict__ W3,
    const float* __restrict__ b3, float* __restrict__ Out, int n)
{
  __shared__ float Hs[64][68];
  __shared__ float W2s[64][32];
  __shared__ float W3s[32][32];
  __shared__ float Us[64][36];
  __shared__ float b2s[32], b3s[32];
  const int t = threadIdx.x;
  const int node0 = blockIdx.x * 64;

#pragma unroll
  for (int i = 0; i < 4; ++i) {
    int lin = t + i * 256;
    int node = lin >> 4, kq = lin & 15;
    float4 v = make_float4(0.f, 0.f, 0.f, 0.f);
    if (node0 + node < n)
      v = *(const float4*)&H4[(size_t)(node0 + node) * 64 + kq * 4];
    *(float4*)&Hs[node][kq * 4] = v;
  }
#pragma unroll
  for (int i = 0; i < 2; ++i) {
    int lin = t + i * 256;
    ((float4*)&W2s[0][0])[lin] = ((const float4*)W2f)[lin];
  }
  ((float4*)&W3s[0][0])[t & 255] = ((const float4*)W3)[t & 255];
  if (t < 32) { b2s[t] = b2f[t]; b3s[t] = b3[t]; }
  __syncthreads();

  const int rg = t >> 4, cg = t & 15;
  float acc[4][2] = {{0.f,0.f},{0.f,0.f},{0.f,0.f},{0.f,0.f}};
#pragma unroll 8
  for (int k = 0; k < 64; ++k) {
    float a[4] = {Hs[rg*4+0][k], Hs[rg*4+1][k], Hs[rg*4+2][k], Hs[rg*4+3][k]};
    float w0 = W2s[k][cg*2], w1 = W2s[k][cg*2+1];
#pragma unroll
    for (int i = 0; i < 4; ++i) { acc[i][0] += a[i]*w0; acc[i][1] += a[i]*w1; }
  }
#pragma unroll
  for (int i = 0; i < 4; ++i) {
    Us[rg*4+i][cg*2+0] = fmaxf(acc[i][0] + b2s[cg*2+0], 0.f);
    Us[rg*4+i][cg*2+1] = fmaxf(acc[i][1] + b2s[cg*2+1], 0.f);
  }
  __syncthreads();

  float acc2[4][2] = {{0.f,0.f},{0.f,0.f},{0.f,0.f},{0.f,0.f}};
#pragma unroll
  for (int k = 0; k < 32; ++k) {
    float a[4] = {Us[rg*4+0][k], Us[rg*4+1][k], Us[rg*4+2][k], Us[rg*4+3][k]};
    float w0 = W3s[k][cg*2], w1 = W3s[k][cg*2+1];
#pragma unroll
    for (int i = 0; i < 4; ++i) { acc2[i][0] += a[i]*w0; acc2[i][1] += a[i]*w1; }
  }
  float (*Os)[36] = (float(*)[36])Hs;
#pragma unroll
  for (int i = 0; i < 4; ++i) {
    Os[rg*4+i][cg*2+0] = acc2[i][0] + b3s[cg*2+0];
    Os[rg*4+i][cg*2+1] = acc2[i][1] + b3s[cg*2+1];
  }
  __syncthreads();
#pragma unroll
  for (int i = 0; i < 2; ++i) {
    int lin = t + i * 256;
    int node = lin >> 3, c4 = lin & 7;
    if (node0 + node < n)
      *(float4*)&Out[(size_t)(node0 + node) * 32 + c4 * 4] =
          *(float4*)&Os[node][c4 * 4];
  }
}

// ---------------------------------------------------------------------------
extern "C" void kernel_launch(void* const* d_in, const int* in_sizes, int n_in,
                              void* d_out, int out_size, void* d_ws, size_t ws_size,
                              hipStream_t stream)
{
  const float* X     = (const float*)d_in[0];
  const float* W1    = (const float*)d_in[1];
  const float* b1    = (const float*)d_in[2];
  const float* Wc1   = (const float*)d_in[3];
  const float* bc1   = (const float*)d_in[4];
  const float* Wc2   = (const float*)d_in[5];
  const float* bc2   = (const float*)d_in[6];
  const float* Wc3   = (const float*)d_in[7];
  const float* bc3   = (const float*)d_in[8];
  const float* gamma = (const float*)d_in[9];
  const float* beta  = (const float*)d_in[10];
  const float* W2    = (const float*)d_in[11];
  const float* b2    = (const float*)d_in[12];
  const float* W3    = (const float*)d_in[13];
  const float* b3    = (const float*)d_in[14];
  const int*   ei    = (const int*)d_in[15];

  const int n  = in_sizes[0] / F_IN;
  const int nE = in_sizes[15] / 2;
  const int* src  = ei;
  const int* dstv = ei + nE;

  const int NB = (n + 511) >> 9;          // buckets of 512 nodes
  const int B  = (nE + 8191) >> 13;       // chunks of 8192 edges
  const int NG = NB * B;
  const int nbG = (NG + 255) / 256;

  float* ws    = (float*)d_ws;
  float* Pa    = ws;                                   // n*64 fp32 (ping)
  float* Pb    = Pa + (size_t)n * D_HID;               // n*64 fp32 (pong)
  float* stats = Pb + (size_t)n * D_HID;               // 128
  float* W2f   = stats + 128;                          // 2048
  float* b2f   = W2f + 2048;                           // 32
  int*   cnt   = (int*)(b2f + 32);                     // n
  int*   offs  = cnt + n;                              // n+1
  int*   G     = offs + n + 1;                         // NG
  int*   W     = G + NG;                               // NG+1
  int*   bsum  = W + NG + 1;                           // nbG+1
  int*   adj   = bsum + nbG + 1;                       // nE
  uintptr_t epAddr = ((uintptr_t)(adj + nE) + 7) & ~(uintptr_t)7;
  int2*  EP    = (int2*)epAddr;                        // nE pairs
  short8* Wt2  = (short8*)(EP + nE);                   // 128KB
  float* H4    = Pb;                                   // reuse Pb (dead after conv3)

  const int nb  = (n + 63) / 64;

  // W1 -> fragment-linear bf16, then fused lin1+conv1 (H1 never hits HBM)
  wt_kernel<<<32, 256, 0, stream>>>(W1, Wt2);
  l1c1_kernel<<<nb, 256, 0, stream>>>(X, Wt2, b1, Wc1, Pa, n);

  // CSR build (bucketed, no global scatter; scan3 folded into read sites)
  hist_kernel<<<B, 256, 0, stream>>>(dstv, G, stats, nE, B, NB);
  scan1_kernel<<<nbG, 256, 0, stream>>>(G, W, bsum, NG);
  scan2_kernel<<<1, 256, 0, stream>>>(bsum, nbG);
  scatter2_kernel<<<B, 256, 0, stream>>>(src, dstv, W, bsum, EP, nE, B, NB);
  fillc_kernel<<<NB, 256, 0, stream>>>(EP, W, bsum, cnt, offs, adj, n, nE, B, NB);

  // conv2: Pb = relu(agg(Pa)/deg + bc1) @ Wc2   (fused gather+pre+mm)
  gmm_kernel<<<nb, 512, 0, stream>>>(Pa, offs, adj, cnt, bc1, Wc2, Pb, n);

  // conv3: Pa = relu(agg(Pb)/deg + bc2) @ Wc3
  gmm_kernel<<<nb, 512, 0, stream>>>(Pb, offs, adj, cnt, bc2, Wc3, Pa, n);

  // conv3 epilogue: H4 = relu(agg(Pa)/deg + bc3); batch stats
  gp_kernel<<<nb, 512, 0, stream>>>(Pa, offs, adj, cnt, bc3, H4, stats, n);

  // fold batchnorm into W2, then fused lin2+lin3
  fold_kernel<<<1, 256, 0, stream>>>(stats, gamma, beta, W2, b2, W2f, b2f, n);
  final_kernel<<<nb, 256, 0, stream>>>(H4, W2f, b2f, W3, b3, (float*)d_out, n);
}

// Round 7
// 601.113 us; speedup vs baseline: 1.2146x; 1.0514x over previous
//
#include <hip/hip_runtime.h>
#include <cstdint>
#include <cstddef>

constexpr int F_IN  = 512;
constexpr int D_EMB = 128;
constexpr int D_HID = 64;
constexpr int N_CLS = 32;

typedef __attribute__((ext_vector_type(8))) short short8;
typedef __attribute__((ext_vector_type(4))) float floatx4;

__device__ inline unsigned short f2bf(float f) {
  union { float f; uint32_t u; } v; v.f = f;
  uint32_t r = v.u + 0x7FFF + ((v.u >> 16) & 1);   // round-to-nearest-even
  return (unsigned short)(r >> 16);
}

__device__ inline uint32_t pack2bf(float lo, float hi) {
  return ((uint32_t)f2bf(hi) << 16) | (uint32_t)f2bf(lo);
}

// ---- W1 -> fragment-linear bf16: Wt2[kc8][ct][ks][lane] of short8 ----------
__global__ __launch_bounds__(256) void wt_kernel(
    const float* __restrict__ W1, short8* __restrict__ Wt2)
{
  int idx = blockIdx.x * 256 + threadIdx.x;     // 0..8191
  int kc8 = idx >> 10, lin = idx & 1023;
  int ct = lin >> 7, rem = lin & 127, ks = rem >> 6, ln = rem & 63;
  int col = ct * 16 + (ln & 15);
  int k0 = kc8 * 64 + ks * 32 + (ln >> 4) * 8;
  short8 s;
#pragma unroll
  for (int j = 0; j < 8; ++j)
    s[j] = (short)f2bf(W1[(size_t)(k0 + j) * D_EMB + col]);
  Wt2[idx] = s;
}

// ---- fused lin1 + conv1-mm: P(bf16) = relu(X @ W1 + b1) @ Wc1 --------------
__global__ __launch_bounds__(256) void l1c1_kernel(
    const float* __restrict__ X, const short8* __restrict__ Wt2,
    const float* __restrict__ b1, const float* __restrict__ Wc1,
    unsigned short* __restrict__ P, int n)
{
  __shared__ __align__(16) char smem[50176];
  short8* Xs = (short8*)smem;                      // 8 KB   (phase 1)
  short8* Ws = (short8*)(smem + 8192);             // 16 KB  (phase 1)
  float (*Hs)[132] = (float(*)[132])smem;          // 33792B (phase 2, aliases)
  float (*Wc)[64]  = (float(*)[64])(smem + 33792); // 16 KB  (phase 2)

  const int t = threadIdx.x;
  const int wave = t >> 6, lane = t & 63;
  const int quad = lane >> 4, mrow = lane & 15;
  const int node0 = blockIdx.x * 64;
  const int cw = wave * 2;                         // col-tile base (2 per wave)

  // phase-2 Wc1 half-0 prefetch: issued now, consumed after the K-loop
  float4 wp[4];
#pragma unroll
  for (int i = 0; i < 4; ++i) wp[i] = ((const float4*)Wc1)[i * 256 + t];

  // X staging assignment: g = t + i*256 (i<2); row = g>>3, col8 = g&7
  const float* sp[2];
  int soff[2];
#pragma unroll
  for (int i = 0; i < 2; ++i) {
    int g = t + i * 256;
    int row = g >> 3, col8 = g & 7;
    soff[i] = row * 128 + ((col8 * 16) ^ ((row & 7) << 4));
    int gr = node0 + row; if (gr >= n) gr = n - 1;
    sp[i] = &X[(size_t)gr * F_IN + col8 * 8];
  }

  floatx4 acc[4][2];
#pragma unroll
  for (int i = 0; i < 4; ++i)
#pragma unroll
    for (int j = 0; j < 2; ++j) acc[i][j] = (floatx4){0.f, 0.f, 0.f, 0.f};

  float4 xrA[2][2], xrB[2][2];    // 2-deep X prefetch (tiles k, k+1)
  short8 wrA[4], wrB[4];          // 2-deep W prefetch

#pragma unroll
  for (int i = 0; i < 2; ++i) {   // prologue: tiles 0 and 1
    xrA[i][0] = *(const float4*)sp[i];
    xrA[i][1] = *(const float4*)(sp[i] + 4);
    xrB[i][0] = *(const float4*)(sp[i] + 64);
    xrB[i][1] = *(const float4*)(sp[i] + 68);
  }
#pragma unroll
  for (int i = 0; i < 4; ++i) {
    wrA[i] = Wt2[t + i * 256];
    wrB[i] = Wt2[1024 + t + i * 256];
  }

  auto substep = [&](float4 (&xr)[2][2], short8 (&wr)[4], int knext) {
    short8 s8[2];
#pragma unroll
    for (int i = 0; i < 2; ++i) {
      s8[i][0] = (short)f2bf(xr[i][0].x); s8[i][1] = (short)f2bf(xr[i][0].y);
      s8[i][2] = (short)f2bf(xr[i][0].z); s8[i][3] = (short)f2bf(xr[i][0].w);
      s8[i][4] = (short)f2bf(xr[i][1].x); s8[i][5] = (short)f2bf(xr[i][1].y);
      s8[i][6] = (short)f2bf(xr[i][1].z); s8[i][7] = (short)f2bf(xr[i][1].w);
    }
    __syncthreads();                      // WAR: prev tile's compute done
#pragma unroll
    for (int i = 0; i < 2; ++i)
      *(short8*)((char*)Xs + soff[i]) = s8[i];
#pragma unroll
    for (int i = 0; i < 4; ++i)
      Ws[t + i * 256] = wr[i];
    __syncthreads();                      // tile visible

    if (knext < 8) {                      // refill this buffer, 2 tiles ahead
#pragma unroll
      for (int i = 0; i < 2; ++i) {
        const float* p = sp[i] + knext * 64;
        xr[i][0] = *(const float4*)p;
        xr[i][1] = *(const float4*)(p + 4);
      }
#pragma unroll
      for (int i = 0; i < 4; ++i)
        wr[i] = Wt2[knext * 1024 + t + i * 256];
    }

#pragma unroll
    for (int ks = 0; ks < 2; ++ks) {
      short8 af[4], bf[2];
#pragma unroll
      for (int rt = 0; rt < 4; ++rt) {
        int row = rt * 16 + mrow;
        int byteoff = row * 128 + ((ks * 64 + quad * 16) ^ ((row & 7) << 4));
        af[rt] = *(const short8*)((const char*)Xs + byteoff);
      }
#pragma unroll
      for (int c = 0; c < 2; ++c)
        bf[c] = Ws[((cw + c) * 2 + ks) * 64 + lane];
#pragma unroll
      for (int rt = 0; rt < 4; ++rt)
#pragma unroll
        for (int c = 0; c < 2; ++c)
          acc[rt][c] = __builtin_amdgcn_mfma_f32_16x16x32_bf16(
              af[rt], bf[c], acc[rt][c], 0, 0, 0);
    }
  };

#pragma unroll 1
  for (int kc8 = 0; kc8 < 8; kc8 += 2) {
    substep(xrA, wrA, kc8 + 2);
    substep(xrB, wrB, kc8 + 3);
  }

  // ---------------- phase 2: P-tile = relu(H1-tile) @ Wc1 -------------------
  __syncthreads();                        // all Xs/Ws reads complete (alias!)
#pragma unroll
  for (int ct = 0; ct < 2; ++ct) {
    int col = (cw + ct) * 16 + mrow;
    float b = b1[col];
#pragma unroll
    for (int rt = 0; rt < 4; ++rt)
#pragma unroll
      for (int r = 0; r < 4; ++r)
        Hs[rt * 16 + quad * 4 + r][col] = fmaxf(acc[rt][ct][r] + b, 0.f);
  }
#pragma unroll
  for (int i = 0; i < 4; ++i)             // Wc1 half 0 into LDS
    ((float4*)&Wc[0][0])[i * 256 + t] = wp[i];
  __syncthreads();

#pragma unroll
  for (int i = 0; i < 4; ++i)             // prefetch Wc1 half 1
    wp[i] = ((const float4*)Wc1)[1024 + i * 256 + t];

  const int rg = t >> 4, cg = t & 15;
  float acc2[4][4];
#pragma unroll
  for (int i = 0; i < 4; ++i)
#pragma unroll
    for (int j = 0; j < 4; ++j) acc2[i][j] = 0.f;

#pragma unroll 8
  for (int k = 0; k < 64; ++k) {          // k = 0..63
    float a[4] = {Hs[rg*4+0][k], Hs[rg*4+1][k], Hs[rg*4+2][k], Hs[rg*4+3][k]};
    float4 b = *(const float4*)&Wc[k][cg * 4];
#pragma unroll
    for (int i = 0; i < 4; ++i) {
      acc2[i][0] += a[i]*b.x; acc2[i][1] += a[i]*b.y;
      acc2[i][2] += a[i]*b.z; acc2[i][3] += a[i]*b.w;
    }
  }
  __syncthreads();
#pragma unroll
  for (int i = 0; i < 4; ++i)             // Wc1 half 1 into LDS
    ((float4*)&Wc[0][0])[i * 256 + t] = wp[i];
  __syncthreads();

#pragma unroll 8
  for (int k = 0; k < 64; ++k) {          // k = 64..127
    float a[4] = {Hs[rg*4+0][64+k], Hs[rg*4+1][64+k],
                  Hs[rg*4+2][64+k], Hs[rg*4+3][64+k]};
    float4 b = *(const float4*)&Wc[k][cg * 4];
#pragma unroll
    for (int i = 0; i < 4; ++i) {
      acc2[i][0] += a[i]*b.x; acc2[i][1] += a[i]*b.y;
      acc2[i][2] += a[i]*b.z; acc2[i][3] += a[i]*b.w;
    }
  }
#pragma unroll
  for (int i = 0; i < 4; ++i) {
    int gn = node0 + rg * 4 + i;
    if (gn < n) {
      uint2 o;
      o.x = pack2bf(acc2[i][0], acc2[i][1]);
      o.y = pack2bf(acc2[i][2], acc2[i][3]);
      *(uint2*)&P[(size_t)gn * 64 + cg * 4] = o;
    }
  }
}

// ---- 2-row gather cores: lane group g=lane>>5 takes alternate edges; ------
// 8-deep unroll (16 edges/iter in flight/wave); shfl_xor(32) merges groups.
// Branchless tail: clamp index to end-1 (dup row = L1 hit), predicate adds.
__device__ inline void gather2_bf(
    const unsigned short* __restrict__ P, const int* __restrict__ adj,
    int beg, int end, int g, int li, float& c0, float& c1)
{
  c0 = 0.f; c1 = 0.f;
  if (end <= beg) return;
  int e1 = end - 1;
  for (int jj = beg + g; jj < end; jj += 16) {
#pragma unroll
    for (int k = 0; k < 8; ++k) {
      int e = jj + 2 * k;
      int ec = min(e, e1);
      int idx = adj[ec];
      uint32_t u = *(const uint32_t*)&P[(size_t)idx * 64 + li * 2];
      float lo = __uint_as_float(u << 16);
      float hi = __uint_as_float(u & 0xFFFF0000u);
      bool p = e < end;
      c0 += p ? lo : 0.f;
      c1 += p ? hi : 0.f;
    }
  }
  c0 += __shfl_xor(c0, 32, 64);
  c1 += __shfl_xor(c1, 32, 64);
}

__device__ inline void gather2_f32(
    const float* __restrict__ P, const int* __restrict__ adj,
    int beg, int end, int g, int li, float& c0, float& c1)
{
  c0 = 0.f; c1 = 0.f;
  if (end <= beg) return;
  int e1 = end - 1;
  for (int jj = beg + g; jj < end; jj += 16) {
#pragma unroll
    for (int k = 0; k < 8; ++k) {
      int e = jj + 2 * k;
      int ec = min(e, e1);
      int idx = adj[ec];
      float2 u = *(const float2*)&P[(size_t)idx * 64 + li * 2];
      bool p = e < end;
      c0 += p ? u.x : 0.f;
      c1 += p ? u.y : 0.f;
    }
  }
  c0 += __shfl_xor(c0, 32, 64);
  c1 += __shfl_xor(c1, 32, 64);
}

// ======= fused gather + pre + matmul: Out = pre(agg(P)) @ W =================
// INBF/OUTBF select bf16 or fp32 storage for P-in / P-out.
template<bool INBF, bool OUTBF>
__global__ __launch_bounds__(512) void gmm_kernel(
    const void* __restrict__ Pv, const int* __restrict__ offs,
    const int* __restrict__ adj, const int* __restrict__ deg,
    const float* __restrict__ bin, const float* __restrict__ W,
    void* __restrict__ Outv, int n)
{
  __shared__ float Hs[64][68];
  __shared__ float Ws[64][64];
  __shared__ int offss[65];
  const int t = threadIdx.x;
  const int wave = t >> 6, lane = t & 63;
  const int g = lane >> 5, li = lane & 31;
  const int node0 = blockIdx.x * 64;

#pragma unroll
  for (int i = 0; i < 2; ++i) {
    int lin = t + i * 512;
    ((float4*)&Ws[0][0])[lin] = ((const float4*)W)[lin];
  }
  if (t < 65) offss[t] = offs[min(node0 + t, n)];
  __syncthreads();

  const float2 bb = *(const float2*)&bin[li * 2];

#pragma unroll 1
  for (int nd = 0; nd < 8; ++nd) {
    int ln = wave * 8 + nd;
    int node = node0 + ln;
    if (node < n) {
      float c0, c1;
      if (INBF)
        gather2_bf((const unsigned short*)Pv, adj, offss[ln], offss[ln + 1],
                   g, li, c0, c1);
      else
        gather2_f32((const float*)Pv, adj, offss[ln], offss[ln + 1],
                    g, li, c0, c1);
      float rd = 1.f / fmaxf((float)deg[node], 1.f);
      float v0 = fmaxf(c0 * rd + bb.x, 0.f);
      float v1 = fmaxf(c1 * rd + bb.y, 0.f);
      if (g == 0) *(float2*)&Hs[ln][li * 2] = make_float2(v0, v1);
    } else if (g == 0) {
      *(float2*)&Hs[ln][li * 2] = make_float2(0.f, 0.f);
    }
  }
  __syncthreads();

  const int rg = t >> 4, cg = t & 15;          // rg 0..31 -> 2 rows each
  float acc[2][4];
#pragma unroll
  for (int i = 0; i < 2; ++i)
#pragma unroll
    for (int j = 0; j < 4; ++j) acc[i][j] = 0.f;

#pragma unroll 8
  for (int k = 0; k < 64; ++k) {
    float a[2] = {Hs[rg * 2 + 0][k], Hs[rg * 2 + 1][k]};
    float4 b = *(const float4*)&Ws[k][cg * 4];
#pragma unroll
    for (int i = 0; i < 2; ++i) {
      acc[i][0] += a[i]*b.x; acc[i][1] += a[i]*b.y;
      acc[i][2] += a[i]*b.z; acc[i][3] += a[i]*b.w;
    }
  }
#pragma unroll
  for (int i = 0; i < 2; ++i) {
    int gn = node0 + rg * 2 + i;
    if (gn < n) {
      if (OUTBF) {
        uint2 o;
        o.x = pack2bf(acc[i][0], acc[i][1]);
        o.y = pack2bf(acc[i][2], acc[i][3]);
        *(uint2*)&((unsigned short*)Outv)[(size_t)gn * 64 + cg * 4] = o;
      } else {
        float4 o = make_float4(acc[i][0], acc[i][1], acc[i][2], acc[i][3]);
        *(float4*)&((float*)Outv)[(size_t)gn * 64 + cg * 4] = o;
      }
    }
  }
}

// ======= fused gather3 + post3 (fp32 P): H4 = relu(agg(P)/deg + bc3) ========
__global__ __launch_bounds__(512) void gp_kernel(
    const float* __restrict__ P, const int* __restrict__ offs,
    const int* __restrict__ adj, const int* __restrict__ deg,
    const float* __restrict__ bc3, float* __restrict__ H4,
    float* __restrict__ stats, int n)
{
  __shared__ int offss[65];
  const int t = threadIdx.x;
  const int wave = t >> 6, lane = t & 63;
  const int g = lane >> 5, li = lane & 31;
  const int node0 = blockIdx.x * 64;
  if (t < 65) offss[t] = offs[min(node0 + t, n)];
  __syncthreads();

  const float2 bb = *(const float2*)&bc3[li * 2];
  float s0 = 0.f, s1 = 0.f, q0 = 0.f, q1 = 0.f;

#pragma unroll 1
  for (int nd = 0; nd < 8; ++nd) {
    int ln = wave * 8 + nd;
    int node = node0 + ln;
    if (node >= n) break;
    float c0, c1;
    gather2_f32(P, adj, offss[ln], offss[ln + 1], g, li, c0, c1);
    float rd = 1.f / fmaxf((float)deg[node], 1.f);
    float v0 = fmaxf(c0 * rd + bb.x, 0.f);
    float v1 = fmaxf(c1 * rd + bb.y, 0.f);
    if (g == 0) *(float2*)&H4[(size_t)node * 64 + li * 2] = make_float2(v0, v1);
    s0 += v0; s1 += v1; q0 += v0 * v0; q1 += v1 * v1;
  }

  __shared__ float red[2][8][64];
  if (g == 0) {
    red[0][wave][li * 2 + 0] = s0; red[0][wave][li * 2 + 1] = s1;
    red[1][wave][li * 2 + 0] = q0; red[1][wave][li * 2 + 1] = q1;
  }
  __syncthreads();
  if (t < 128) {
    int which = t >> 6, ff = t & 63;
    float a = 0.f;
#pragma unroll
    for (int w = 0; w < 8; ++w) a += red[which][w][ff];
    atomicAdd(&stats[which * 64 + ff], a);
  }
}

// ============== CSR build: bucketed, no global scatter ======================
__global__ __launch_bounds__(256) void hist_kernel(
    const int* __restrict__ dst, int* __restrict__ G,
    float* __restrict__ stats, int nE, int B, int NB)
{
  __shared__ int h[256];
  int blk = blockIdx.x, t = threadIdx.x;
  if (blk == 0 && t < 128) stats[t] = 0.f;     // folded stats memset
  h[t] = 0;
  __syncthreads();
  int base = blk * 8192;
  int lim = min(8192, nE - base);
  for (int i = t; i < lim; i += 256)
    atomicAdd(&h[dst[base + i] >> 9], 1);
  __syncthreads();
  if (t < NB) G[t * B + blk] = h[t];
}

__global__ __launch_bounds__(256) void scan1_kernel(
    const int* __restrict__ in, int* __restrict__ out,
    int* __restrict__ bsum, int n)
{
  __shared__ int sh[256];
  int t = threadIdx.x;
  int i = blockIdx.x * 256 + t;
  int c = (i < n) ? in[i] : 0;
  sh[t] = c;
  __syncthreads();
#pragma unroll
  for (int off = 1; off < 256; off <<= 1) {
    int v = 0;
    if (t >= off) v = sh[t - off];
    __syncthreads();
    if (t >= off) sh[t] += v;
    __syncthreads();
  }
  if (i < n) out[i] = sh[t] - c;
  if (t == 255) bsum[blockIdx.x] = sh[255];
}

__global__ __launch_bounds__(256) void scan2_kernel(int* __restrict__ bsum, int nb)
{
  __shared__ int sh[256];
  __shared__ int carry;
  int t = threadIdx.x;
  if (t == 0) carry = 0;
  __syncthreads();
  for (int base = 0; base < nb; base += 256) {
    int i = base + t;
    int v = (i < nb) ? bsum[i] : 0;
    sh[t] = v;
    __syncthreads();
#pragma unroll
    for (int off = 1; off < 256; off <<= 1) {
      int u = 0;
      if (t >= off) u = sh[t - off];
      __syncthreads();
      if (t >= off) sh[t] += u;
      __syncthreads();
    }
    int c0 = carry;
    int incl = sh[t], total = sh[255];
    if (i < nb) bsum[i] = c0 + incl - v;
    __syncthreads();
    if (t == 0) carry = c0 + total;
    __syncthreads();
  }
  if (t == 0) bsum[nb] = carry;
}

// scatter edges into bucket-major pair array; block-exclusive regions
__global__ __launch_bounds__(256) void scatter2_kernel(
    const int* __restrict__ src, const int* __restrict__ dst,
    const int* __restrict__ W, const int* __restrict__ bsum,
    int2* __restrict__ EP, int nE, int B, int NB)
{
  __shared__ int cur[256];
  int blk = blockIdx.x, t = threadIdx.x;
  if (t < NB) {
    int gi = t * B + blk;
    cur[t] = W[gi] + bsum[gi >> 8];
  }
  __syncthreads();
  int base = blk * 8192;
  int lim = min(8192, nE - base);
  for (int i = t; i < lim; i += 256) {
    int s = src[base + i], d = dst[base + i];
    int slot = atomicAdd(&cur[d >> 9], 1);
    EP[slot] = make_int2(s, d);
  }
}

// per-bucket: cnt/offs from LDS hist+scan; adj fill in block-local window
__global__ __launch_bounds__(256) void fillc_kernel(
    const int2* __restrict__ EP, const int* __restrict__ W,
    const int* __restrict__ bsum,
    int* __restrict__ cnt, int* __restrict__ offs, int* __restrict__ adj,
    int n, int nE, int B, int NB)
{
  __shared__ int h[512];
  int b = blockIdx.x, t = threadIdx.x;
  int g0i = b * B;
  int segStart = W[g0i] + bsum[g0i >> 8];
  int segEnd = (b == NB - 1) ? nE : (W[g0i + B] + bsum[(g0i + B) >> 8]);
  int nodeBase = b << 9;

  h[t] = 0; h[t + 256] = 0;
  __syncthreads();
  for (int i = segStart + t; i < segEnd; i += 256)
    atomicAdd(&h[EP[i].y - nodeBase], 1);
  __syncthreads();
  int c0 = h[t], c1 = h[t + 256];
#pragma unroll
  for (int off = 1; off < 512; off <<= 1) {
    int a = (t >= off) ? h[t - off] : 0;
    int bb = (t + 256 >= off) ? h[t + 256 - off] : 0;
    __syncthreads();
    h[t] += a; h[t + 256] += bb;
    __syncthreads();
  }
  int e0 = h[t] - c0, e1 = h[t + 256] - c1;   // exclusive
  int g0 = nodeBase + t, g1 = nodeBase + t + 256;
  if (g0 < n) { cnt[g0] = c0; offs[g0] = segStart + e0; }
  if (g1 < n) { cnt[g1] = c1; offs[g1] = segStart + e1; }
  if (b == 0 && t == 0) offs[n] = nE;
  __syncthreads();
  h[t] = e0; h[t + 256] = e1;                 // cursors
  __syncthreads();
  for (int i = segStart + t; i < segEnd; i += 256) {
    int2 p = EP[i];
    int slot = atomicAdd(&h[p.y - nodeBase], 1);
    adj[segStart + slot] = p.x;
  }
}

// ---- fold batchnorm into W2 ------------------------------------------------
__global__ __launch_bounds__(256) void fold_kernel(
    const float* __restrict__ stats, const float* __restrict__ gamma,
    const float* __restrict__ beta, const float* __restrict__ W2,
    const float* __restrict__ b2, float* __restrict__ W2f,
    float* __restrict__ b2f, int n)
{
  __shared__ float rsg[64], corr[64];
  int t = threadIdx.x;
  if (t < 64) {
    float m = stats[t] / (float)n;
    float var = stats[64 + t] / (float)n - m * m;
    float rs = rsqrtf(var + 1e-5f);
    float g = gamma[t] * rs;
    rsg[t] = g;
    corr[t] = beta[t] - m * g;
  }
  __syncthreads();
#pragma unroll
  for (int i = 0; i < 8; ++i) {
    int lin = t + i * 256;
    int k = lin >> 5;
    W2f[lin] = rsg[k] * W2[lin];
  }
  if (t < 32) {
    float a = b2[t];
    for (int k = 0; k < 64; ++k) a += corr[k] * W2[k * 32 + t];
    b2f[t] = a;
  }
}

// ---- final: out = relu(H4 @ W2f + b2f) @ W3 + b3 ---------------------------
__global__ __launch_bounds__(256) void final_kernel(
    const float* __restrict__ H4, const float* __restrict__ W2f,
    const float* __restrict__ b2f, const float* __restrict__ W3,
    const float* __restrict__ b3, float* __restrict__ Out, int n)
{
  __shared__ float Hs[64][68];
  __shared__ float W2s[64][32];
  __shared__ float W3s[32][32];
  __shared__ float Us[64][36];
  __shared__ float b2s[32], b3s[32];
  const int t = threadIdx.x;
  const int node0 = blockIdx.x * 64;

#pragma unroll
  for (int i = 0; i < 4; ++i) {
    int lin = t + i * 256;
    int node = lin >> 4, kq = lin & 15;
    float4 v = make_float4(0.f, 0.f, 0.f, 0.f);
    if (node0 + node < n)
      v = *(const float4*)&H4[(size_t)(node0 + node) * 64 + kq * 4];
    *(float4*)&Hs[node][kq * 4] = v;
  }
#pragma unroll
  for (int i = 0; i < 2; ++i) {
    int lin = t + i * 256;
    ((float4*)&W2s[0][0])[lin] = ((const float4*)W2f)[lin];
  }
  ((float4*)&W3s[0][0])[t & 255] = ((const float4*)W3)[t & 255];
  if (t < 32) { b2s[t] = b2f[t]; b3s[t] = b3[t]; }
  __syncthreads();

  const int rg = t >> 4, cg = t & 15;
  float acc[4][2] = {{0.f,0.f},{0.f,0.f},{0.f,0.f},{0.f,0.f}};
#pragma unroll 8
  for (int k = 0; k < 64; ++k) {
    float a[4] = {Hs[rg*4+0][k], Hs[rg*4+1][k], Hs[rg*4+2][k], Hs[rg*4+3][k]};
    float w0 = W2s[k][cg*2], w1 = W2s[k][cg*2+1];
#pragma unroll
    for (int i = 0; i < 4; ++i) { acc[i][0] += a[i]*w0; acc[i][1] += a[i]*w1; }
  }
#pragma unroll
  for (int i = 0; i < 4; ++i) {
    Us[rg*4+i][cg*2+0] = fmaxf(acc[i][0] + b2s[cg*2+0], 0.f);
    Us[rg*4+i][cg*2+1] = fmaxf(acc[i][1] + b2s[cg*2+1], 0.f);
  }
  __syncthreads();

  float acc2[4][2] = {{0.f,0.f},{0.f,0.f},{0.f,0.f},{0.f,0.f}};
#pragma unroll
  for (int k = 0; k < 32; ++k) {
    float a[4] = {Us[rg*4+0][k], Us[rg*4+1][k], Us[rg*4+2][k], Us[rg*4+3][k]};
    float w0 = W3s[k][cg*2], w1 = W3s[k][cg*2+1];
#pragma unroll
    for (int i = 0; i < 4; ++i) { acc2[i][0] += a[i]*w0; acc2[i][1] += a[i]*w1; }
  }
  float (*Os)[36] = (float(*)[36])Hs;
#pragma unroll
  for (int i = 0; i < 4; ++i) {
    Os[rg*4+i][cg*2+0] = acc2[i][0] + b3s[cg*2+0];
    Os[rg*4+i][cg*2+1] = acc2[i][1] + b3s[cg*2+1];
  }
  __syncthreads();
#pragma unroll
  for (int i = 0; i < 2; ++i) {
    int lin = t + i * 256;
    int node = lin >> 3, c4 = lin & 7;
    if (node0 + node < n)
      *(float4*)&Out[(size_t)(node0 + node) * 32 + c4 * 4] =
          *(float4*)&Os[node][c4 * 4];
  }
}

// ---------------------------------------------------------------------------
extern "C" void kernel_launch(void* const* d_in, const int* in_sizes, int n_in,
                              void* d_out, int out_size, void* d_ws, size_t ws_size,
                              hipStream_t stream)
{
  const float* X     = (const float*)d_in[0];
  const float* W1    = (const float*)d_in[1];
  const float* b1    = (const float*)d_in[2];
  const float* Wc1   = (const float*)d_in[3];
  const float* bc1   = (const float*)d_in[4];
  const float* Wc2   = (const float*)d_in[5];
  const float* bc2   = (const float*)d_in[6];
  const float* Wc3   = (const float*)d_in[7];
  const float* bc3   = (const float*)d_in[8];
  const float* gamma = (const float*)d_in[9];
  const float* beta  = (const float*)d_in[10];
  const float* W2    = (const float*)d_in[11];
  const float* b2    = (const float*)d_in[12];
  const float* W3    = (const float*)d_in[13];
  const float* b3    = (const float*)d_in[14];
  const int*   ei    = (const int*)d_in[15];

  const int n  = in_sizes[0] / F_IN;
  const int nE = in_sizes[15] / 2;
  const int* src  = ei;
  const int* dstv = ei + nE;

  const int NB = (n + 511) >> 9;          // buckets of 512 nodes
  const int B  = (nE + 8191) >> 13;       // chunks of 8192 edges
  const int NG = NB * B;
  const int nbG = (NG + 255) / 256;

  char* wsb = (char*)d_ws;
  unsigned short* Pa = (unsigned short*)wsb;               // n*64 bf16
  unsigned short* Pb = (unsigned short*)(wsb + (size_t)n * 128); // n*64 bf16
  float* Pc    = (float*)(wsb + (size_t)n * 256);          // n*64 fp32
  float* H4    = (float*)(wsb + (size_t)n * 512);          // n*64 fp32
  float* stats = H4 + (size_t)n * 64;                      // 128
  float* W2f   = stats + 128;                              // 2048
  float* b2f   = W2f + 2048;                               // 32
  int*   cnt   = (int*)(b2f + 32);                         // n
  int*   offs  = cnt + n;                                  // n+1
  int*   G     = offs + n + 1;                             // NG
  int*   W     = G + NG;                                   // NG+1
  int*   bsum  = W + NG + 1;                               // nbG+1
  int*   adj   = bsum + nbG + 1;                           // nE
  uintptr_t epAddr = ((uintptr_t)(adj + nE) + 7) & ~(uintptr_t)7;
  int2*  EP    = (int2*)epAddr;                            // nE pairs
  short8* Wt2  = (short8*)(EP + nE);                       // 128KB

  const int nb  = (n + 63) / 64;

  // W1 -> fragment-linear bf16, then fused lin1+conv1 (H1 never hits HBM)
  wt_kernel<<<32, 256, 0, stream>>>(W1, Wt2);
  l1c1_kernel<<<nb, 256, 0, stream>>>(X, Wt2, b1, Wc1, Pa, n);

  // CSR build (bucketed, no global scatter; scan3 folded into read sites)
  hist_kernel<<<B, 256, 0, stream>>>(dstv, G, stats, nE, B, NB);
  scan1_kernel<<<nbG, 256, 0, stream>>>(G, W, bsum, NG);
  scan2_kernel<<<1, 256, 0, stream>>>(bsum, nbG);
  scatter2_kernel<<<B, 256, 0, stream>>>(src, dstv, W, bsum, EP, nE, B, NB);
  fillc_kernel<<<NB, 256, 0, stream>>>(EP, W, bsum, cnt, offs, adj, n, nE, B, NB);

  // conv2: Pb(bf16) = relu(agg(Pa bf16)/deg + bc1) @ Wc2
  gmm_kernel<true, true><<<nb, 512, 0, stream>>>(
      Pa, offs, adj, cnt, bc1, Wc2, Pb, n);

  // conv3: Pc(fp32) = relu(agg(Pb bf16)/deg + bc2) @ Wc3
  gmm_kernel<true, false><<<nb, 512, 0, stream>>>(
      Pb, offs, adj, cnt, bc2, Wc3, Pc, n);

  // conv3 epilogue: H4 = relu(agg(Pc fp32)/deg + bc3); batch stats
  gp_kernel<<<nb, 512, 0, stream>>>(Pc, offs, adj, cnt, bc3, H4, stats, n);

  // fold batchnorm into W2, then fused lin2+lin3
  fold_kernel<<<1, 256, 0, stream>>>(stats, gamma, beta, W2, b2, W2f, b2f, n);
  final_kernel<<<nb, 256, 0, stream>>>(H4, W2f, b2f, W3, b3, (float*)d_out, n);
}